// Round 4
// baseline (908.658 us; speedup 1.0000x reference)
//
#include <hip/hip_runtime.h>
#include <hip/hip_bf16.h>
#include <math.h>

#define NTHREADS 256
#define BR 64

typedef __attribute__((ext_vector_type(8))) short   s16x8;
typedef __attribute__((ext_vector_type(8))) __bf16  bf16x8;
typedef __attribute__((ext_vector_type(4))) float   f32x4;

// ---- Compile-time hash-grid constants (verified exact: absmax 0.0 rounds 1&3) ----
__device__ __constant__ float c_scale[16] = {
    15.0f,        21.110607f,  29.554930f,  41.224254f,
    57.350239f,   79.634946f,  110.430473f, 152.987205f,
    211.796890f,  293.066769f, 405.374657f, 560.574388f,
    775.046906f,  1071.429232f, 1481.003616f, 2047.0f
};
__device__ __constant__ unsigned c_off[16] = {
    0u,        4920u,     18744u,    51512u,
    136696u,   352696u,   876984u,   1401272u,
    1925560u,  2449848u,  2974136u,  3498424u,
    4022712u,  4547000u,  5071288u,  5595576u
};
__device__ __constant__ unsigned c_res1[16] = {
    17u, 24u, 32u, 44u, 60u, 0u,0u,0u,0u,0u,0u,0u,0u,0u,0u,0u
};

__device__ inline unsigned short f2bf(float f) {
    unsigned u = __builtin_bit_cast(unsigned, f);
    u += 0x7FFFu + ((u >> 16) & 1u);          // round-to-nearest-even
    return (unsigned short)(u >> 16);
}
__device__ inline float bf2f(unsigned short h) {
    unsigned u = ((unsigned)h) << 16;
    return __builtin_bit_cast(float, u);
}
__device__ inline f32x4 mfma_bf16(s16x8 a, s16x8 b, f32x4 c) {
    return __builtin_amdgcn_mfma_f32_16x16x32_bf16(
        __builtin_bit_cast(bf16x8, a), __builtin_bit_cast(bf16x8, b), c, 0, 0, 0);
}

// ws layout (bytes): wt (bf16 weights, transposed) @0 ; bf16 table @278528 ;
// feature planes uint2[8][N] @24758984-aligned (see launch).
__global__ void convert_w(const float* __restrict__ w1, const float* __restrict__ w2,
                          const float* __restrict__ w3, unsigned short* __restrict__ ws) {
    int t = blockIdx.x * blockDim.x + threadIdx.x;
    if (t < 8192) {
        int col = t >> 5, k = t & 31;
        ws[t] = f2bf(w1[k * 256 + col]);
    } else if (t < 73728) {
        int u = t - 8192; int col = u >> 8, k = u & 255;
        ws[t] = f2bf(w2[k * 256 + col]);
    } else if (t < 139264) {
        int u = t - 73728; int col = u >> 8, k = u & 255;
        ws[t] = f2bf(w3[k * 256 + col]);
    }
}

__global__ void convert_table(const float* __restrict__ t, unsigned short* __restrict__ o, int n4) {
    int i = blockIdx.x * blockDim.x + threadIdx.x;
    if (i < n4) {
        float4 v = ((const float4*)t)[i];
        ushort4 r;
        r.x = f2bf(v.x); r.y = f2bf(v.y); r.z = f2bf(v.z); r.w = f2bf(v.w);
        ((ushort4*)o)[i] = r;
    }
}

// ---- encode: thread = (point, level-pair). No LDS -> max occupancy. ----
// feat2 layout: uint2[lpair][N]; uint2 = {bf16x2(l=2lp), bf16x2(l=2lp+1)}.
__global__ __launch_bounds__(256)
void encode_kernel(const float* __restrict__ x, const unsigned short* __restrict__ tbf,
                   uint2* __restrict__ feat2, int N)
{
    const int p  = blockIdx.x * 256 + threadIdx.x;
    const int lp = blockIdx.y;                 // 0..7, wave-uniform
    if (p >= N) return;

    const float inv = (1.0f / 1.5f);
    const float xc = x[3 * p + 0] * inv;
    const float yc = x[3 * p + 1] * inv;
    const float zc = x[3 * p + 2] * inv;

    unsigned outv[2];
    #pragma unroll
    for (int s = 0; s < 2; ++s) {
        const int l = lp * 2 + s;              // uniform
        const float sc = c_scale[l];
        const float px = xc * sc + 0.5f;
        const float py = yc * sc + 0.5f;
        const float pz = zc * sc + 0.5f;
        const float fx = floorf(px), fy = floorf(py), fz = floorf(pz);
        const float rx = px - fx, ry = py - fy, rz = pz - fz;
        const unsigned ux = (unsigned)fx, uy = (unsigned)fy, uz = (unsigned)fz;
        const unsigned off = c_off[l];
        const unsigned r1  = c_res1[l];
        const bool dense = (l < 5);            // uniform
        float ax = 0.0f, ay = 0.0f;
        #pragma unroll
        for (int c = 0; c < 8; ++c) {
            const unsigned bx = c & 1, by = (c >> 1) & 1, bz = (c >> 2) & 1;
            const unsigned cx = ux + bx, cy = uy + by, cz = uz + bz;
            const float wx = bx ? rx : (1.0f - rx);
            const float wy = by ? ry : (1.0f - ry);
            const float wz = bz ? rz : (1.0f - rz);
            const float w = wx * wy * wz;
            unsigned idx;
            if (dense) idx = cx + cy * r1 + cz * r1 * r1;
            else       idx = (cx ^ (cy * 2654435761u) ^ (cz * 805459861u)) & 524287u;
            const unsigned v = *reinterpret_cast<const unsigned*>(tbf + 2u * (idx + off));
            ax = fmaf(w, bf2f((unsigned short)(v & 0xFFFFu)), ax);
            ay = fmaf(w, bf2f((unsigned short)(v >> 16)), ay);
        }
        outv[s] = (unsigned)f2bf(ax) | ((unsigned)f2bf(ay) << 16);
    }
    feat2[(size_t)lp * N + p] = make_uint2(outv[0], outv[1]);   // 512B/wave coalesced
}

// ---- MLP: round-3 MFMA structure, A-tile from feature planes ----
__global__ __launch_bounds__(NTHREADS, 4)
void mlp_kernel(const uint2* __restrict__ feat2,
                const unsigned short* __restrict__ wt,
                const float* __restrict__ b1, const float* __restrict__ b2,
                const float* __restrict__ b3,
                const float* __restrict__ w4, const float* __restrict__ b4,
                float* __restrict__ out, int N)
{
    __shared__ unsigned short sA[BR * 256];   // 32 KB, rows of 512B, XOR-swizzled
    char* sAb = (char*)sA;

    const int tid = threadIdx.x;
    const int p0  = blockIdx.x * BR;
    if (p0 >= N) return;

    // ---- A-tile load: 512 uint2 (8 planes x 64 points), coalesced reads ----
    #pragma unroll
    for (int it = 0; it < 2; ++it) {
        const int t  = it * NTHREADS + tid;
        const int lp = t >> 6;                 // plane 0..7, wave-quarter-uniform
        const int p  = t & 63;
        const uint2 v = feat2[(size_t)lp * N + p0 + p];
        *reinterpret_cast<uint2*>(
            sAb + p * 512 + (((unsigned)(lp * 8)) ^ ((unsigned)((p & 7) << 4)))) = v;
    }
    __syncthreads();

    const int lane = tid & 63;
    const int wid  = tid >> 6;
    const int colb = wid * 64;
    const int arow = lane & 15;
    const int kgrp = lane >> 4;
    const int bcol = lane & 15;

    f32x4 acc[4][4];

    auto epilogue = [&](const float* __restrict__ bias) {
        float bv[4];
        #pragma unroll
        for (int ct = 0; ct < 4; ++ct) bv[ct] = bias[colb + ct * 16 + bcol];
        #pragma unroll
        for (int rt = 0; rt < 4; ++rt) {
            #pragma unroll
            for (int r = 0; r < 4; ++r) {
                const int row = rt * 16 + kgrp * 4 + r;
                char* rp = sAb + row * 512;
                const unsigned sw = (unsigned)((row & 7) << 4);
                #pragma unroll
                for (int ct = 0; ct < 4; ++ct) {
                    const int col = colb + ct * 16 + bcol;
                    const float v = fmaxf(acc[rt][ct][r] + bv[ct], 0.0f);
                    *reinterpret_cast<unsigned short*>(rp + (((unsigned)(col * 2)) ^ sw)) = f2bf(v);
                }
            }
        }
    };

    // ---- layer 1 ----
    {
        #pragma unroll
        for (int rt = 0; rt < 4; ++rt)
            #pragma unroll
            for (int ct = 0; ct < 4; ++ct) acc[rt][ct] = f32x4{0.f, 0.f, 0.f, 0.f};

        s16x8 afr[4];
        #pragma unroll
        for (int rt = 0; rt < 4; ++rt) {
            const int row = rt * 16 + arow;
            afr[rt] = *reinterpret_cast<const s16x8*>(
                sAb + row * 512 + (((unsigned)(kgrp * 16)) ^ ((unsigned)((row & 7) << 4))));
        }
        #pragma unroll
        for (int ct = 0; ct < 4; ++ct) {
            const int col = colb + ct * 16 + bcol;
            const s16x8 bfr = *reinterpret_cast<const s16x8*>(wt + col * 32 + kgrp * 8);
            #pragma unroll
            for (int rt = 0; rt < 4; ++rt)
                acc[rt][ct] = mfma_bf16(afr[rt], bfr, acc[rt][ct]);
        }
        __syncthreads();
        epilogue(b1);
        __syncthreads();
    }

    // ---- layers 2 & 3 ----
    #pragma unroll 1
    for (int layer = 0; layer < 2; ++layer) {
        const unsigned short* __restrict__ W = wt + 8192 + (layer << 16);
        #pragma unroll
        for (int rt = 0; rt < 4; ++rt)
            #pragma unroll
            for (int ct = 0; ct < 4; ++ct) acc[rt][ct] = f32x4{0.f, 0.f, 0.f, 0.f};

        for (int ks = 0; ks < 8; ++ks) {
            s16x8 afr[4];
            #pragma unroll
            for (int rt = 0; rt < 4; ++rt) {
                const int row = rt * 16 + arow;
                afr[rt] = *reinterpret_cast<const s16x8*>(
                    sAb + row * 512 + (((unsigned)(ks * 64 + kgrp * 16)) ^ ((unsigned)((row & 7) << 4))));
            }
            #pragma unroll
            for (int ct = 0; ct < 4; ++ct) {
                const s16x8 bfr = *reinterpret_cast<const s16x8*>(
                    W + (colb + ct * 16 + bcol) * 256 + ks * 32 + kgrp * 8);
                #pragma unroll
                for (int rt = 0; rt < 4; ++rt)
                    acc[rt][ct] = mfma_bf16(afr[rt], bfr, acc[rt][ct]);
            }
        }
        __syncthreads();
        epilogue(layer == 0 ? b2 : b3);
        __syncthreads();
    }

    // ---- layer 4 + sigmoid ----
    if (tid < BR * 3) {
        const int r = tid / 3;
        const int c = tid - 3 * r;
        float z = 0.0f;
        for (int kb = 0; kb < 32; ++kb) {
            const s16x8 hv = *reinterpret_cast<const s16x8*>(
                sAb + r * 512 + (((unsigned)(kb * 16)) ^ ((unsigned)((r & 7) << 4))));
            #pragma unroll
            for (int j = 0; j < 8; ++j)
                z = fmaf(bf2f((unsigned short)hv[j]), w4[(kb * 8 + j) * 3 + c], z);
        }
        z += b4[c];
        const int pi = p0 + r;
        if (pi < N) out[pi * 3 + c] = 1.0f / (1.0f + expf(-z));
    }
}

// ---- round-3 fused kernel kept as ws_size fallback (verified passing) ----
template<bool BFT>
__global__ __launch_bounds__(NTHREADS, 3)
void fused_hashmlp(const float* __restrict__ x, const float* __restrict__ table,
                   const unsigned short* __restrict__ tbf,
                   const unsigned short* __restrict__ wt,
                   const float* __restrict__ b1, const float* __restrict__ b2,
                   const float* __restrict__ b3,
                   const float* __restrict__ w4, const float* __restrict__ b4,
                   float* __restrict__ out, int N)
{
    __shared__ float sX[BR][3];
    __shared__ unsigned short sA[BR * 256];
    const int tid = threadIdx.x;
    const int p0  = blockIdx.x * BR;
    if (p0 >= N) return;
    char* sAb = (char*)sA;

    if (tid < BR * 3) sX[tid / 3][tid % 3] = x[p0 * 3 + tid];
    __syncthreads();

    #pragma unroll
    for (int it = 0; it < 4; ++it) {
        const int task = it * NTHREADS + tid;
        const int l = task >> 6;
        const int p = task & 63;
        const float sc  = c_scale[l];
        const float inv = (1.0f / 1.5f);
        const float px = sX[p][0] * inv * sc + 0.5f;
        const float py = sX[p][1] * inv * sc + 0.5f;
        const float pz = sX[p][2] * inv * sc + 0.5f;
        const float fx = floorf(px), fy = floorf(py), fz = floorf(pz);
        const float rx = px - fx, ry = py - fy, rz = pz - fz;
        const unsigned ux = (unsigned)fx, uy = (unsigned)fy, uz = (unsigned)fz;
        const unsigned off = c_off[l];
        const unsigned r1  = c_res1[l];
        const bool dense = (l < 5);
        float ax = 0.0f, ay = 0.0f;
        #pragma unroll
        for (int c = 0; c < 8; ++c) {
            const unsigned bx = c & 1, by = (c >> 1) & 1, bz = (c >> 2) & 1;
            const unsigned cx = ux + bx, cy = uy + by, cz = uz + bz;
            const float wx = bx ? rx : (1.0f - rx);
            const float wy = by ? ry : (1.0f - ry);
            const float wz = bz ? rz : (1.0f - rz);
            const float w = wx * wy * wz;
            unsigned idx;
            if (dense) idx = cx + cy * r1 + cz * r1 * r1;
            else       idx = (cx ^ (cy * 2654435761u) ^ (cz * 805459861u)) & 524287u;
            float tx, ty;
            if (BFT) {
                const unsigned v = *reinterpret_cast<const unsigned*>(tbf + 2u * (idx + off));
                tx = bf2f((unsigned short)(v & 0xFFFFu));
                ty = bf2f((unsigned short)(v >> 16));
            } else {
                const float2 tv = *reinterpret_cast<const float2*>(table + 2u * (idx + off));
                tx = tv.x; ty = tv.y;
            }
            ax = fmaf(w, tx, ax);
            ay = fmaf(w, ty, ay);
        }
        const unsigned pack = (unsigned)f2bf(ax) | ((unsigned)f2bf(ay) << 16);
        *reinterpret_cast<unsigned*>(sAb + p * 512 + ((l * 4) ^ ((p & 7) << 4))) = pack;
    }
    __syncthreads();

    const int lane = tid & 63;
    const int wid  = tid >> 6;
    const int colb = wid * 64;
    const int arow = lane & 15;
    const int kgrp = lane >> 4;
    const int bcol = lane & 15;

    f32x4 acc[4][4];

    auto epilogue = [&](const float* __restrict__ bias) {
        float bv[4];
        #pragma unroll
        for (int ct = 0; ct < 4; ++ct) bv[ct] = bias[colb + ct * 16 + bcol];
        #pragma unroll
        for (int rt = 0; rt < 4; ++rt) {
            #pragma unroll
            for (int r = 0; r < 4; ++r) {
                const int row = rt * 16 + kgrp * 4 + r;
                char* rp = sAb + row * 512;
                const unsigned sw = (unsigned)((row & 7) << 4);
                #pragma unroll
                for (int ct = 0; ct < 4; ++ct) {
                    const int col = colb + ct * 16 + bcol;
                    const float v = fmaxf(acc[rt][ct][r] + bv[ct], 0.0f);
                    *reinterpret_cast<unsigned short*>(rp + (((unsigned)(col * 2)) ^ sw)) = f2bf(v);
                }
            }
        }
    };

    {
        #pragma unroll
        for (int rt = 0; rt < 4; ++rt)
            #pragma unroll
            for (int ct = 0; ct < 4; ++ct) acc[rt][ct] = f32x4{0.f, 0.f, 0.f, 0.f};
        s16x8 afr[4];
        #pragma unroll
        for (int rt = 0; rt < 4; ++rt) {
            const int row = rt * 16 + arow;
            afr[rt] = *reinterpret_cast<const s16x8*>(
                sAb + row * 512 + (((unsigned)(kgrp * 16)) ^ ((unsigned)((row & 7) << 4))));
        }
        #pragma unroll
        for (int ct = 0; ct < 4; ++ct) {
            const int col = colb + ct * 16 + bcol;
            const s16x8 bfr = *reinterpret_cast<const s16x8*>(wt + col * 32 + kgrp * 8);
            #pragma unroll
            for (int rt = 0; rt < 4; ++rt)
                acc[rt][ct] = mfma_bf16(afr[rt], bfr, acc[rt][ct]);
        }
        __syncthreads();
        epilogue(b1);
        __syncthreads();
    }

    #pragma unroll 1
    for (int layer = 0; layer < 2; ++layer) {
        const unsigned short* __restrict__ W = wt + 8192 + (layer << 16);
        #pragma unroll
        for (int rt = 0; rt < 4; ++rt)
            #pragma unroll
            for (int ct = 0; ct < 4; ++ct) acc[rt][ct] = f32x4{0.f, 0.f, 0.f, 0.f};
        for (int ks = 0; ks < 8; ++ks) {
            s16x8 afr[4];
            #pragma unroll
            for (int rt = 0; rt < 4; ++rt) {
                const int row = rt * 16 + arow;
                afr[rt] = *reinterpret_cast<const s16x8*>(
                    sAb + row * 512 + (((unsigned)(ks * 64 + kgrp * 16)) ^ ((unsigned)((row & 7) << 4))));
            }
            #pragma unroll
            for (int ct = 0; ct < 4; ++ct) {
                const s16x8 bfr = *reinterpret_cast<const s16x8*>(
                    W + (colb + ct * 16 + bcol) * 256 + ks * 32 + kgrp * 8);
                #pragma unroll
                for (int rt = 0; rt < 4; ++rt)
                    acc[rt][ct] = mfma_bf16(afr[rt], bfr, acc[rt][ct]);
            }
        }
        __syncthreads();
        epilogue(layer == 0 ? b2 : b3);
        __syncthreads();
    }

    if (tid < BR * 3) {
        const int r = tid / 3;
        const int c = tid - 3 * r;
        float z = 0.0f;
        for (int kb = 0; kb < 32; ++kb) {
            const s16x8 hv = *reinterpret_cast<const s16x8*>(
                sAb + r * 512 + (((unsigned)(kb * 16)) ^ ((unsigned)((r & 7) << 4))));
            #pragma unroll
            for (int j = 0; j < 8; ++j)
                z = fmaf(bf2f((unsigned short)hv[j]), w4[(kb * 8 + j) * 3 + c], z);
        }
        z += b4[c];
        const int pi = p0 + r;
        if (pi < N) out[pi * 3 + c] = 1.0f / (1.0f + expf(-z));
    }
}

extern "C" void kernel_launch(void* const* d_in, const int* in_sizes, int n_in,
                              void* d_out, int out_size, void* d_ws, size_t ws_size,
                              hipStream_t stream) {
    const float* x     = (const float*)d_in[0];
    const float* table = (const float*)d_in[1];
    const float* w1    = (const float*)d_in[2];
    const float* b1    = (const float*)d_in[3];
    const float* w2    = (const float*)d_in[4];
    const float* b2    = (const float*)d_in[5];
    const float* w3    = (const float*)d_in[6];
    const float* b3    = (const float*)d_in[7];
    const float* w4    = (const float*)d_in[8];
    const float* b4    = (const float*)d_in[9];
    float* out = (float*)d_out;

    const int N = in_sizes[0] / 3;

    const size_t W_ELEMS    = 139264;                   // bf16 weight elements
    const size_t TBL_ELEMS  = 12239728;                 // 2 * TOTAL bf16 table elements
    const size_t need_bf    = (W_ELEMS + TBL_ELEMS) * 2;   // 24.76 MB
    const size_t FEAT_BYTES = (size_t)N * 64;              // uint2[8][N]
    const size_t need_split = need_bf + FEAT_BYTES;        // ~58.3 MB

    unsigned short* wsw = (unsigned short*)d_ws;
    unsigned short* tbf = wsw + W_ELEMS;
    uint2* feat2 = (uint2*)((char*)d_ws + need_bf);     // 8B-aligned (need_bf % 8 == 0)

    hipLaunchKernelGGL(convert_w, dim3(544), dim3(256), 0, stream, w1, w2, w3, wsw);

    if (ws_size >= need_split) {
        const size_t n4 = TBL_ELEMS / 4;
        hipLaunchKernelGGL(convert_table, dim3((unsigned)((n4 + 255) / 256)), dim3(256), 0, stream,
                           table, tbf, (int)n4);
        hipLaunchKernelGGL(encode_kernel, dim3((N + 255) / 256, 8), dim3(256), 0, stream,
                           x, tbf, feat2, N);
        hipLaunchKernelGGL(mlp_kernel, dim3((N + BR - 1) / BR), dim3(NTHREADS), 0, stream,
                           feat2, wsw, b1, b2, b3, w4, b4, out, N);
    } else if (ws_size >= need_bf) {
        const size_t n4 = TBL_ELEMS / 4;
        hipLaunchKernelGGL(convert_table, dim3((unsigned)((n4 + 255) / 256)), dim3(256), 0, stream,
                           table, tbf, (int)n4);
        hipLaunchKernelGGL(fused_hashmlp<true>, dim3((N + BR - 1) / BR), dim3(NTHREADS), 0, stream,
                           x, table, tbf, wsw, b1, b2, b3, w4, b4, out, N);
    } else {
        hipLaunchKernelGGL(fused_hashmlp<false>, dim3((N + BR - 1) / BR), dim3(NTHREADS), 0, stream,
                           x, table, tbf, wsw, b1, b2, b3, w4, b4, out, N);
    }
}

// Round 6
// 710.030 us; speedup vs baseline: 1.2797x; 1.2797x over previous
//
#include <hip/hip_runtime.h>
#include <hip/hip_bf16.h>
#include <math.h>

#define NTHREADS 256
#define BR 64

typedef __attribute__((ext_vector_type(8))) short   s16x8;
typedef __attribute__((ext_vector_type(8))) __bf16  bf16x8;
typedef __attribute__((ext_vector_type(4))) float   f32x4;

// ---- Compile-time hash-grid constants (verified exact: absmax 0.0 rounds 1,3,4) ----
__device__ __constant__ float c_scale[16] = {
    15.0f,        21.110607f,  29.554930f,  41.224254f,
    57.350239f,   79.634946f,  110.430473f, 152.987205f,
    211.796890f,  293.066769f, 405.374657f, 560.574388f,
    775.046906f,  1071.429232f, 1481.003616f, 2047.0f
};
__device__ __constant__ unsigned c_off[16] = {
    0u,        4920u,     18744u,    51512u,
    136696u,   352696u,   876984u,   1401272u,
    1925560u,  2449848u,  2974136u,  3498424u,
    4022712u,  4547000u,  5071288u,  5595576u
};
__device__ __constant__ unsigned c_res1[16] = {
    17u, 24u, 32u, 44u, 60u, 0u,0u,0u,0u,0u,0u,0u,0u,0u,0u,0u
};

__device__ inline unsigned short f2bf(float f) {
    unsigned u = __builtin_bit_cast(unsigned, f);
    u += 0x7FFFu + ((u >> 16) & 1u);          // round-to-nearest-even
    return (unsigned short)(u >> 16);
}
__device__ inline float bf2f(unsigned short h) {
    unsigned u = ((unsigned)h) << 16;
    return __builtin_bit_cast(float, u);
}
__device__ inline f32x4 mfma_bf16(s16x8 a, s16x8 b, f32x4 c) {
    return __builtin_amdgcn_mfma_f32_16x16x32_bf16(
        __builtin_bit_cast(bf16x8, a), __builtin_bit_cast(bf16x8, b), c, 0, 0, 0);
}

// ws layout (bytes): wt (bf16 weights, transposed) @0 ; bf16 table @278528 ;
// feature planes uint2[8][N] after that (see launch).
__global__ void convert_w(const float* __restrict__ w1, const float* __restrict__ w2,
                          const float* __restrict__ w3, unsigned short* __restrict__ ws) {
    int t = blockIdx.x * blockDim.x + threadIdx.x;
    if (t < 8192) {
        int col = t >> 5, k = t & 31;
        ws[t] = f2bf(w1[k * 256 + col]);
    } else if (t < 73728) {
        int u = t - 8192; int col = u >> 8, k = u & 255;
        ws[t] = f2bf(w2[k * 256 + col]);
    } else if (t < 139264) {
        int u = t - 73728; int col = u >> 8, k = u & 255;
        ws[t] = f2bf(w3[k * 256 + col]);
    }
}

__global__ void convert_table(const float* __restrict__ t, unsigned short* __restrict__ o, int n4) {
    int i = blockIdx.x * blockDim.x + threadIdx.x;
    if (i < n4) {
        float4 v = ((const float4*)t)[i];
        ushort4 r;
        r.x = f2bf(v.x); r.y = f2bf(v.y); r.z = f2bf(v.z); r.w = f2bf(v.w);
        ((ushort4*)o)[i] = r;
    }
}

// ---- encode: thread = (point, level-pair). No LDS -> max occupancy. ----
// feat2 layout: uint2[lpair][N]; uint2 = {bf16x2(l=2lp), bf16x2(l=2lp+1)}.
__global__ __launch_bounds__(256)
void encode_kernel(const float* __restrict__ x, const unsigned short* __restrict__ tbf,
                   uint2* __restrict__ feat2, int N)
{
    const int p  = blockIdx.x * 256 + threadIdx.x;
    const int lp = blockIdx.y;                 // 0..7, wave-uniform
    if (p >= N) return;

    const float inv = (1.0f / 1.5f);
    const float xc = x[3 * p + 0] * inv;
    const float yc = x[3 * p + 1] * inv;
    const float zc = x[3 * p + 2] * inv;

    unsigned outv[2];
    #pragma unroll
    for (int s = 0; s < 2; ++s) {
        const int l = lp * 2 + s;              // uniform
        const float sc = c_scale[l];
        const float px = xc * sc + 0.5f;
        const float py = yc * sc + 0.5f;
        const float pz = zc * sc + 0.5f;
        const float fx = floorf(px), fy = floorf(py), fz = floorf(pz);
        const float rx = px - fx, ry = py - fy, rz = pz - fz;
        const unsigned ux = (unsigned)fx, uy = (unsigned)fy, uz = (unsigned)fz;
        const unsigned off = c_off[l];
        const unsigned r1  = c_res1[l];
        const bool dense = (l < 5);            // uniform
        float ax = 0.0f, ay = 0.0f;
        #pragma unroll
        for (int c = 0; c < 8; ++c) {
            const unsigned bx = c & 1, by = (c >> 1) & 1, bz = (c >> 2) & 1;
            const unsigned cx = ux + bx, cy = uy + by, cz = uz + bz;
            const float wx = bx ? rx : (1.0f - rx);
            const float wy = by ? ry : (1.0f - ry);
            const float wz = bz ? rz : (1.0f - rz);
            const float w = wx * wy * wz;
            unsigned idx;
            if (dense) idx = cx + cy * r1 + cz * r1 * r1;
            else       idx = (cx ^ (cy * 2654435761u) ^ (cz * 805459861u)) & 524287u;
            const unsigned v = *reinterpret_cast<const unsigned*>(tbf + 2u * (idx + off));
            ax = fmaf(w, bf2f((unsigned short)(v & 0xFFFFu)), ax);
            ay = fmaf(w, bf2f((unsigned short)(v >> 16)), ay);
        }
        outv[s] = (unsigned)f2bf(ax) | ((unsigned)f2bf(ay) << 16);
    }
    feat2[(size_t)lp * N + p] = make_uint2(outv[0], outv[1]);   // 512B/wave coalesced
}

// ---- MLP: MFMA structure, A-tile from feature planes ----
// __launch_bounds__(256,3): 170-reg budget -> acc(64 AGPR)+arch(~84)=148 fits, NO SPILL.
// (256,4) capped at 128 regs and spilled acc -> 1 GB scratch traffic, 615us (round 4).
__global__ __launch_bounds__(NTHREADS, 3)
void mlp_kernel(const uint2* __restrict__ feat2,
                const unsigned short* __restrict__ wt,
                const float* __restrict__ b1, const float* __restrict__ b2,
                const float* __restrict__ b3,
                const float* __restrict__ w4, const float* __restrict__ b4,
                float* __restrict__ out, int N)
{
    __shared__ unsigned short sA[BR * 256];   // 32 KB, rows of 512B, XOR-swizzled
    char* sAb = (char*)sA;

    const int tid = threadIdx.x;
    const int p0  = blockIdx.x * BR;
    if (p0 >= N) return;

    // ---- A-tile load: 512 uint2 (8 planes x 64 points), coalesced reads ----
    #pragma unroll
    for (int it = 0; it < 2; ++it) {
        const int t  = it * NTHREADS + tid;
        const int lp = t >> 6;                 // plane 0..7
        const int p  = t & 63;
        const uint2 v = feat2[(size_t)lp * N + p0 + p];
        *reinterpret_cast<uint2*>(
            sAb + p * 512 + (((unsigned)(lp * 8)) ^ ((unsigned)((p & 7) << 4)))) = v;
    }
    __syncthreads();

    const int lane = tid & 63;
    const int wid  = tid >> 6;
    const int colb = wid * 64;
    const int arow = lane & 15;
    const int kgrp = lane >> 4;
    const int bcol = lane & 15;

    f32x4 acc[4][4];

    auto epilogue = [&](const float* __restrict__ bias) {
        float bv[4];
        #pragma unroll
        for (int ct = 0; ct < 4; ++ct) bv[ct] = bias[colb + ct * 16 + bcol];
        #pragma unroll
        for (int rt = 0; rt < 4; ++rt) {
            #pragma unroll
            for (int r = 0; r < 4; ++r) {
                const int row = rt * 16 + kgrp * 4 + r;
                char* rp = sAb + row * 512;
                const unsigned sw = (unsigned)((row & 7) << 4);
                #pragma unroll
                for (int ct = 0; ct < 4; ++ct) {
                    const int col = colb + ct * 16 + bcol;
                    const float v = fmaxf(acc[rt][ct][r] + bv[ct], 0.0f);
                    *reinterpret_cast<unsigned short*>(rp + (((unsigned)(col * 2)) ^ sw)) = f2bf(v);
                }
            }
        }
    };

    // ---- layer 1 ----
    {
        #pragma unroll
        for (int rt = 0; rt < 4; ++rt)
            #pragma unroll
            for (int ct = 0; ct < 4; ++ct) acc[rt][ct] = f32x4{0.f, 0.f, 0.f, 0.f};

        s16x8 afr[4];
        #pragma unroll
        for (int rt = 0; rt < 4; ++rt) {
            const int row = rt * 16 + arow;
            afr[rt] = *reinterpret_cast<const s16x8*>(
                sAb + row * 512 + (((unsigned)(kgrp * 16)) ^ ((unsigned)((row & 7) << 4))));
        }
        #pragma unroll
        for (int ct = 0; ct < 4; ++ct) {
            const int col = colb + ct * 16 + bcol;
            const s16x8 bfr = *reinterpret_cast<const s16x8*>(wt + col * 32 + kgrp * 8);
            #pragma unroll
            for (int rt = 0; rt < 4; ++rt)
                acc[rt][ct] = mfma_bf16(afr[rt], bfr, acc[rt][ct]);
        }
        __syncthreads();
        epilogue(b1);
        __syncthreads();
    }

    // ---- layers 2 & 3 ----
    #pragma unroll 1
    for (int layer = 0; layer < 2; ++layer) {
        const unsigned short* __restrict__ W = wt + 8192 + (layer << 16);
        #pragma unroll
        for (int rt = 0; rt < 4; ++rt)
            #pragma unroll
            for (int ct = 0; ct < 4; ++ct) acc[rt][ct] = f32x4{0.f, 0.f, 0.f, 0.f};

        for (int ks = 0; ks < 8; ++ks) {
            s16x8 afr[4];
            #pragma unroll
            for (int rt = 0; rt < 4; ++rt) {
                const int row = rt * 16 + arow;
                afr[rt] = *reinterpret_cast<const s16x8*>(
                    sAb + row * 512 + (((unsigned)(ks * 64 + kgrp * 16)) ^ ((unsigned)((row & 7) << 4))));
            }
            #pragma unroll
            for (int ct = 0; ct < 4; ++ct) {
                const s16x8 bfr = *reinterpret_cast<const s16x8*>(
                    W + (colb + ct * 16 + bcol) * 256 + ks * 32 + kgrp * 8);
                #pragma unroll
                for (int rt = 0; rt < 4; ++rt)
                    acc[rt][ct] = mfma_bf16(afr[rt], bfr, acc[rt][ct]);
            }
        }
        __syncthreads();
        epilogue(layer == 0 ? b2 : b3);
        __syncthreads();
    }

    // ---- layer 4 + sigmoid ----
    if (tid < BR * 3) {
        const int r = tid / 3;
        const int c = tid - 3 * r;
        float z = 0.0f;
        for (int kb = 0; kb < 32; ++kb) {
            const s16x8 hv = *reinterpret_cast<const s16x8*>(
                sAb + r * 512 + (((unsigned)(kb * 16)) ^ ((unsigned)((r & 7) << 4))));
            #pragma unroll
            for (int j = 0; j < 8; ++j)
                z = fmaf(bf2f((unsigned short)hv[j]), w4[(kb * 8 + j) * 3 + c], z);
        }
        z += b4[c];
        const int pi = p0 + r;
        if (pi < N) out[pi * 3 + c] = 1.0f / (1.0f + expf(-z));
    }
}

// ---- round-3 fused kernel kept as ws_size fallback (verified passing) ----
template<bool BFT>
__global__ __launch_bounds__(NTHREADS, 3)
void fused_hashmlp(const float* __restrict__ x, const float* __restrict__ table,
                   const unsigned short* __restrict__ tbf,
                   const unsigned short* __restrict__ wt,
                   const float* __restrict__ b1, const float* __restrict__ b2,
                   const float* __restrict__ b3,
                   const float* __restrict__ w4, const float* __restrict__ b4,
                   float* __restrict__ out, int N)
{
    __shared__ float sX[BR][3];
    __shared__ unsigned short sA[BR * 256];
    const int tid = threadIdx.x;
    const int p0  = blockIdx.x * BR;
    if (p0 >= N) return;
    char* sAb = (char*)sA;

    if (tid < BR * 3) sX[tid / 3][tid % 3] = x[p0 * 3 + tid];
    __syncthreads();

    #pragma unroll
    for (int it = 0; it < 4; ++it) {
        const int task = it * NTHREADS + tid;
        const int l = task >> 6;
        const int p = task & 63;
        const float sc  = c_scale[l];
        const float inv = (1.0f / 1.5f);
        const float px = sX[p][0] * inv * sc + 0.5f;
        const float py = sX[p][1] * inv * sc + 0.5f;
        const float pz = sX[p][2] * inv * sc + 0.5f;
        const float fx = floorf(px), fy = floorf(py), fz = floorf(pz);
        const float rx = px - fx, ry = py - fy, rz = pz - fz;
        const unsigned ux = (unsigned)fx, uy = (unsigned)fy, uz = (unsigned)fz;
        const unsigned off = c_off[l];
        const unsigned r1  = c_res1[l];
        const bool dense = (l < 5);
        float ax = 0.0f, ay = 0.0f;
        #pragma unroll
        for (int c = 0; c < 8; ++c) {
            const unsigned bx = c & 1, by = (c >> 1) & 1, bz = (c >> 2) & 1;
            const unsigned cx = ux + bx, cy = uy + by, cz = uz + bz;
            const float wx = bx ? rx : (1.0f - rx);
            const float wy = by ? ry : (1.0f - ry);
            const float wz = bz ? rz : (1.0f - rz);
            const float w = wx * wy * wz;
            unsigned idx;
            if (dense) idx = cx + cy * r1 + cz * r1 * r1;
            else       idx = (cx ^ (cy * 2654435761u) ^ (cz * 805459861u)) & 524287u;
            float tx, ty;
            if (BFT) {
                const unsigned v = *reinterpret_cast<const unsigned*>(tbf + 2u * (idx + off));
                tx = bf2f((unsigned short)(v & 0xFFFFu));
                ty = bf2f((unsigned short)(v >> 16));
            } else {
                const float2 tv = *reinterpret_cast<const float2*>(table + 2u * (idx + off));
                tx = tv.x; ty = tv.y;
            }
            ax = fmaf(w, tx, ax);
            ay = fmaf(w, ty, ay);
        }
        const unsigned pack = (unsigned)f2bf(ax) | ((unsigned)f2bf(ay) << 16);
        *reinterpret_cast<unsigned*>(sAb + p * 512 + ((l * 4) ^ ((p & 7) << 4))) = pack;
    }
    __syncthreads();

    const int lane = tid & 63;
    const int wid  = tid >> 6;
    const int colb = wid * 64;
    const int arow = lane & 15;
    const int kgrp = lane >> 4;
    const int bcol = lane & 15;

    f32x4 acc[4][4];

    auto epilogue = [&](const float* __restrict__ bias) {
        float bv[4];
        #pragma unroll
        for (int ct = 0; ct < 4; ++ct) bv[ct] = bias[colb + ct * 16 + bcol];
        #pragma unroll
        for (int rt = 0; rt < 4; ++rt) {
            #pragma unroll
            for (int r = 0; r < 4; ++r) {
                const int row = rt * 16 + kgrp * 4 + r;
                char* rp = sAb + row * 512;
                const unsigned sw = (unsigned)((row & 7) << 4);
                #pragma unroll
                for (int ct = 0; ct < 4; ++ct) {
                    const int col = colb + ct * 16 + bcol;
                    const float v = fmaxf(acc[rt][ct][r] + bv[ct], 0.0f);
                    *reinterpret_cast<unsigned short*>(rp + (((unsigned)(col * 2)) ^ sw)) = f2bf(v);
                }
            }
        }
    };

    {
        #pragma unroll
        for (int rt = 0; rt < 4; ++rt)
            #pragma unroll
            for (int ct = 0; ct < 4; ++ct) acc[rt][ct] = f32x4{0.f, 0.f, 0.f, 0.f};
        s16x8 afr[4];
        #pragma unroll
        for (int rt = 0; rt < 4; ++rt) {
            const int row = rt * 16 + arow;
            afr[rt] = *reinterpret_cast<const s16x8*>(
                sAb + row * 512 + (((unsigned)(kgrp * 16)) ^ ((unsigned)((row & 7) << 4))));
        }
        #pragma unroll
        for (int ct = 0; ct < 4; ++ct) {
            const int col = colb + ct * 16 + bcol;
            const s16x8 bfr = *reinterpret_cast<const s16x8*>(wt + col * 32 + kgrp * 8);
            #pragma unroll
            for (int rt = 0; rt < 4; ++rt)
                acc[rt][ct] = mfma_bf16(afr[rt], bfr, acc[rt][ct]);
        }
        __syncthreads();
        epilogue(b1);
        __syncthreads();
    }

    #pragma unroll 1
    for (int layer = 0; layer < 2; ++layer) {
        const unsigned short* __restrict__ W = wt + 8192 + (layer << 16);
        #pragma unroll
        for (int rt = 0; rt < 4; ++rt)
            #pragma unroll
            for (int ct = 0; ct < 4; ++ct) acc[rt][ct] = f32x4{0.f, 0.f, 0.f, 0.f};
        for (int ks = 0; ks < 8; ++ks) {
            s16x8 afr[4];
            #pragma unroll
            for (int rt = 0; rt < 4; ++rt) {
                const int row = rt * 16 + arow;
                afr[rt] = *reinterpret_cast<const s16x8*>(
                    sAb + row * 512 + (((unsigned)(ks * 64 + kgrp * 16)) ^ ((unsigned)((row & 7) << 4))));
            }
            #pragma unroll
            for (int ct = 0; ct < 4; ++ct) {
                const s16x8 bfr = *reinterpret_cast<const s16x8*>(
                    W + (colb + ct * 16 + bcol) * 256 + ks * 32 + kgrp * 8);
                #pragma unroll
                for (int rt = 0; rt < 4; ++rt)
                    acc[rt][ct] = mfma_bf16(afr[rt], bfr, acc[rt][ct]);
            }
        }
        __syncthreads();
        epilogue(layer == 0 ? b2 : b3);
        __syncthreads();
    }

    if (tid < BR * 3) {
        const int r = tid / 3;
        const int c = tid - 3 * r;
        float z = 0.0f;
        for (int kb = 0; kb < 32; ++kb) {
            const s16x8 hv = *reinterpret_cast<const s16x8*>(
                sAb + r * 512 + (((unsigned)(kb * 16)) ^ ((unsigned)((r & 7) << 4))));
            #pragma unroll
            for (int j = 0; j < 8; ++j)
                z = fmaf(bf2f((unsigned short)hv[j]), w4[(kb * 8 + j) * 3 + c], z);
        }
        z += b4[c];
        const int pi = p0 + r;
        if (pi < N) out[pi * 3 + c] = 1.0f / (1.0f + expf(-z));
    }
}

extern "C" void kernel_launch(void* const* d_in, const int* in_sizes, int n_in,
                              void* d_out, int out_size, void* d_ws, size_t ws_size,
                              hipStream_t stream) {
    const float* x     = (const float*)d_in[0];
    const float* table = (const float*)d_in[1];
    const float* w1    = (const float*)d_in[2];
    const float* b1    = (const float*)d_in[3];
    const float* w2    = (const float*)d_in[4];
    const float* b2    = (const float*)d_in[5];
    const float* w3    = (const float*)d_in[6];
    const float* b3    = (const float*)d_in[7];
    const float* w4    = (const float*)d_in[8];
    const float* b4    = (const float*)d_in[9];
    float* out = (float*)d_out;

    const int N = in_sizes[0] / 3;

    const size_t W_ELEMS    = 139264;                   // bf16 weight elements
    const size_t TBL_ELEMS  = 12239728;                 // 2 * TOTAL bf16 table elements
    const size_t need_bf    = (W_ELEMS + TBL_ELEMS) * 2;   // 24.76 MB
    const size_t FEAT_BYTES = (size_t)N * 64;              // uint2[8][N]
    const size_t need_split = need_bf + FEAT_BYTES;        // ~58.3 MB

    unsigned short* wsw = (unsigned short*)d_ws;
    unsigned short* tbf = wsw + W_ELEMS;
    uint2* feat2 = (uint2*)((char*)d_ws + need_bf);     // 8B-aligned (need_bf % 8 == 0)

    hipLaunchKernelGGL(convert_w, dim3(544), dim3(256), 0, stream, w1, w2, w3, wsw);

    if (ws_size >= need_split) {
        const size_t n4 = TBL_ELEMS / 4;
        hipLaunchKernelGGL(convert_table, dim3((unsigned)((n4 + 255) / 256)), dim3(256), 0, stream,
                           table, tbf, (int)n4);
        hipLaunchKernelGGL(encode_kernel, dim3((N + 255) / 256, 8), dim3(256), 0, stream,
                           x, tbf, feat2, N);
        hipLaunchKernelGGL(mlp_kernel, dim3((N + BR - 1) / BR), dim3(NTHREADS), 0, stream,
                           feat2, wsw, b1, b2, b3, w4, b4, out, N);
    } else if (ws_size >= need_bf) {
        const size_t n4 = TBL_ELEMS / 4;
        hipLaunchKernelGGL(convert_table, dim3((unsigned)((n4 + 255) / 256)), dim3(256), 0, stream,
                           table, tbf, (int)n4);
        hipLaunchKernelGGL(fused_hashmlp<true>, dim3((N + BR - 1) / BR), dim3(NTHREADS), 0, stream,
                           x, table, tbf, wsw, b1, b2, b3, w4, b4, out, N);
    } else {
        hipLaunchKernelGGL(fused_hashmlp<false>, dim3((N + BR - 1) / BR), dim3(NTHREADS), 0, stream,
                           x, table, tbf, wsw, b1, b2, b3, w4, b4, out, N);
    }
}

// Round 7
// 664.845 us; speedup vs baseline: 1.3667x; 1.0680x over previous
//
#include <hip/hip_runtime.h>
#include <hip/hip_bf16.h>
#include <math.h>

#define NTHREADS 256
#define BR 64

typedef __attribute__((ext_vector_type(8))) short   s16x8;
typedef __attribute__((ext_vector_type(8))) __bf16  bf16x8;
typedef __attribute__((ext_vector_type(4))) float   f32x4;

// ---- Compile-time hash-grid constants (verified exact: absmax 0.0 rounds 1,3,4,6) ----
__device__ __constant__ float c_scale[16] = {
    15.0f,        21.110607f,  29.554930f,  41.224254f,
    57.350239f,   79.634946f,  110.430473f, 152.987205f,
    211.796890f,  293.066769f, 405.374657f, 560.574388f,
    775.046906f,  1071.429232f, 1481.003616f, 2047.0f
};
__device__ __constant__ unsigned c_off[16] = {
    0u,        4920u,     18744u,    51512u,
    136696u,   352696u,   876984u,   1401272u,
    1925560u,  2449848u,  2974136u,  3498424u,
    4022712u,  4547000u,  5071288u,  5595576u
};
__device__ __constant__ unsigned c_res1[16] = {
    17u, 24u, 32u, 44u, 60u, 0u,0u,0u,0u,0u,0u,0u,0u,0u,0u,0u
};

__device__ inline unsigned short f2bf(float f) {
    unsigned u = __builtin_bit_cast(unsigned, f);
    u += 0x7FFFu + ((u >> 16) & 1u);          // round-to-nearest-even
    return (unsigned short)(u >> 16);
}
__device__ inline float bf2f(unsigned short h) {
    unsigned u = ((unsigned)h) << 16;
    return __builtin_bit_cast(float, u);
}
__device__ inline f32x4 mfma_bf16(s16x8 a, s16x8 b, f32x4 c) {
    return __builtin_amdgcn_mfma_f32_16x16x32_bf16(
        __builtin_bit_cast(bf16x8, a), __builtin_bit_cast(bf16x8, b), c, 0, 0, 0);
}

// ws layout (bytes): wt (bf16 weights, transposed wt[o][k]) @0 ; bf16 table @278528 ;
// feature planes uint2[8][N] after that (see launch).
__global__ void convert_w(const float* __restrict__ w1, const float* __restrict__ w2,
                          const float* __restrict__ w3, unsigned short* __restrict__ ws) {
    int t = blockIdx.x * blockDim.x + threadIdx.x;
    if (t < 8192) {
        int col = t >> 5, k = t & 31;
        ws[t] = f2bf(w1[k * 256 + col]);
    } else if (t < 73728) {
        int u = t - 8192; int col = u >> 8, k = u & 255;
        ws[t] = f2bf(w2[k * 256 + col]);
    } else if (t < 139264) {
        int u = t - 73728; int col = u >> 8, k = u & 255;
        ws[t] = f2bf(w3[k * 256 + col]);
    }
}

__global__ void convert_table(const float* __restrict__ t, unsigned short* __restrict__ o, int n4) {
    int i = blockIdx.x * blockDim.x + threadIdx.x;
    if (i < n4) {
        float4 v = ((const float4*)t)[i];
        ushort4 r;
        r.x = f2bf(v.x); r.y = f2bf(v.y); r.z = f2bf(v.z); r.w = f2bf(v.w);
        ((ushort4*)o)[i] = r;
    }
}

// ---- encode: thread = (point, level-pair). No LDS -> max occupancy. ----
__global__ __launch_bounds__(256)
void encode_kernel(const float* __restrict__ x, const unsigned short* __restrict__ tbf,
                   uint2* __restrict__ feat2, int N)
{
    const int p  = blockIdx.x * 256 + threadIdx.x;
    const int lp = blockIdx.y;                 // 0..7, wave-uniform
    if (p >= N) return;

    const float inv = (1.0f / 1.5f);
    const float xc = x[3 * p + 0] * inv;
    const float yc = x[3 * p + 1] * inv;
    const float zc = x[3 * p + 2] * inv;

    unsigned outv[2];
    #pragma unroll
    for (int s = 0; s < 2; ++s) {
        const int l = lp * 2 + s;              // uniform
        const float sc = c_scale[l];
        const float px = xc * sc + 0.5f;
        const float py = yc * sc + 0.5f;
        const float pz = zc * sc + 0.5f;
        const float fx = floorf(px), fy = floorf(py), fz = floorf(pz);
        const float rx = px - fx, ry = py - fy, rz = pz - fz;
        const unsigned ux = (unsigned)fx, uy = (unsigned)fy, uz = (unsigned)fz;
        const unsigned off = c_off[l];
        const unsigned r1  = c_res1[l];
        const bool dense = (l < 5);            // uniform
        float ax = 0.0f, ay = 0.0f;
        #pragma unroll
        for (int c = 0; c < 8; ++c) {
            const unsigned bx = c & 1, by = (c >> 1) & 1, bz = (c >> 2) & 1;
            const unsigned cx = ux + bx, cy = uy + by, cz = uz + bz;
            const float wx = bx ? rx : (1.0f - rx);
            const float wy = by ? ry : (1.0f - ry);
            const float wz = bz ? rz : (1.0f - rz);
            const float w = wx * wy * wz;
            unsigned idx;
            if (dense) idx = cx + cy * r1 + cz * r1 * r1;
            else       idx = (cx ^ (cy * 2654435761u) ^ (cz * 805459861u)) & 524287u;
            const unsigned v = *reinterpret_cast<const unsigned*>(tbf + 2u * (idx + off));
            ax = fmaf(w, bf2f((unsigned short)(v & 0xFFFFu)), ax);
            ay = fmaf(w, bf2f((unsigned short)(v >> 16)), ay);
        }
        outv[s] = (unsigned)f2bf(ax) | ((unsigned)f2bf(ay) << 16);
    }
    feat2[(size_t)lp * N + p] = make_uint2(outv[0], outv[1]);   // 512B/wave coalesced
}

// ---- MLP (transposed operands): A = weights wt[o][k], B = activations sA[p][k].
// D[row=feature][col=point] -> each lane's 4 acc values are 4 CONSECUTIVE features of
// one point -> packed ds_write_b64, conflict-free (was 64x ds_write_b16 with 4-way
// conflicts -> SQ_LDS_BANK_CONFLICT 1.23e7, the round-6 hotspot).
// __launch_bounds__(256,3): 170-reg budget, no spill (round-4 lesson: (256,4) spills).
__global__ __launch_bounds__(NTHREADS, 3)
void mlp_kernel(const uint2* __restrict__ feat2,
                const unsigned short* __restrict__ wt,
                const float* __restrict__ b1, const float* __restrict__ b2,
                const float* __restrict__ b3,
                const float* __restrict__ w4, const float* __restrict__ b4,
                float* __restrict__ out, int N)
{
    __shared__ unsigned short sA[BR * 256];   // 32 KB, rows of 512B, XOR-swizzled
    char* sAb = (char*)sA;

    const int tid = threadIdx.x;
    const int p0  = blockIdx.x * BR;
    if (p0 >= N) return;

    // ---- A-tile load: 512 uint2 (8 planes x 64 points), coalesced reads ----
    #pragma unroll
    for (int it = 0; it < 2; ++it) {
        const int t  = it * NTHREADS + tid;
        const int lp = t >> 6;                 // plane 0..7
        const int p  = t & 63;
        const uint2 v = feat2[(size_t)lp * N + p0 + p];
        *reinterpret_cast<uint2*>(
            sAb + p * 512 + (((unsigned)(lp * 8)) ^ ((unsigned)((p & 7) << 4)))) = v;
    }
    __syncthreads();

    const int lane = tid & 63;
    const int wid  = tid >> 6;
    const int rowb = wid * 64;           // wave's 64-FEATURE slice (output rows)
    const int arow = lane & 15;          // A-frag row  = output feature (within 16)
    const int kgrp = lane >> 4;          // k-offset group (k0 = kgrp*8)
    const int bcol = lane & 15;          // B-frag col   = point (within 16)

    f32x4 acc[4][4];                     // [feature-tile rt][point-tile ct]

    auto epilogue = [&](const float* __restrict__ bias) {
        #pragma unroll
        for (int rt = 0; rt < 4; ++rt) {
            const int f0 = rowb + rt * 16 + kgrp * 4;       // 4 consecutive features
            const float4 bv = *reinterpret_cast<const float4*>(bias + f0);
            #pragma unroll
            for (int ct = 0; ct < 4; ++ct) {
                const int p = ct * 16 + bcol;
                const float v0 = fmaxf(acc[rt][ct][0] + bv.x, 0.0f);
                const float v1 = fmaxf(acc[rt][ct][1] + bv.y, 0.0f);
                const float v2 = fmaxf(acc[rt][ct][2] + bv.z, 0.0f);
                const float v3 = fmaxf(acc[rt][ct][3] + bv.w, 0.0f);
                uint2 pk;
                pk.x = (unsigned)f2bf(v0) | ((unsigned)f2bf(v1) << 16);
                pk.y = (unsigned)f2bf(v2) | ((unsigned)f2bf(v3) << 16);
                *reinterpret_cast<uint2*>(
                    sAb + p * 512 + (((unsigned)(2 * f0)) ^ ((unsigned)((p & 7) << 4)))) = pk;
            }
        }
    };

    // ---- layer 1: K=32, single MFMA per (rt,ct) ----
    {
        #pragma unroll
        for (int rt = 0; rt < 4; ++rt)
            #pragma unroll
            for (int ct = 0; ct < 4; ++ct) acc[rt][ct] = f32x4{0.f, 0.f, 0.f, 0.f};

        s16x8 wfr[4];
        #pragma unroll
        for (int rt = 0; rt < 4; ++rt)
            wfr[rt] = *reinterpret_cast<const s16x8*>(wt + (rowb + rt * 16 + arow) * 32 + kgrp * 8);
        #pragma unroll
        for (int ct = 0; ct < 4; ++ct) {
            const int p = ct * 16 + bcol;
            const s16x8 bfr = *reinterpret_cast<const s16x8*>(
                sAb + p * 512 + (((unsigned)(kgrp * 16)) ^ ((unsigned)((p & 7) << 4))));
            #pragma unroll
            for (int rt = 0; rt < 4; ++rt)
                acc[rt][ct] = mfma_bf16(wfr[rt], bfr, acc[rt][ct]);
        }
        __syncthreads();
        epilogue(b1);
        __syncthreads();
    }

    // ---- layers 2 & 3: K=256 ----
    #pragma unroll 1
    for (int layer = 0; layer < 2; ++layer) {
        const unsigned short* __restrict__ W = wt + 8192 + (layer << 16);
        #pragma unroll
        for (int rt = 0; rt < 4; ++rt)
            #pragma unroll
            for (int ct = 0; ct < 4; ++ct) acc[rt][ct] = f32x4{0.f, 0.f, 0.f, 0.f};

        for (int ks = 0; ks < 8; ++ks) {
            s16x8 wfr[4];
            #pragma unroll
            for (int rt = 0; rt < 4; ++rt)
                wfr[rt] = *reinterpret_cast<const s16x8*>(
                    W + (rowb + rt * 16 + arow) * 256 + ks * 32 + kgrp * 8);
            #pragma unroll
            for (int ct = 0; ct < 4; ++ct) {
                const int p = ct * 16 + bcol;
                const s16x8 bfr = *reinterpret_cast<const s16x8*>(
                    sAb + p * 512 + (((unsigned)(ks * 64 + kgrp * 16)) ^ ((unsigned)((p & 7) << 4))));
                #pragma unroll
                for (int rt = 0; rt < 4; ++rt)
                    acc[rt][ct] = mfma_bf16(wfr[rt], bfr, acc[rt][ct]);
            }
        }
        __syncthreads();
        epilogue(layer == 0 ? b2 : b3);
        __syncthreads();
    }

    // ---- layer 4: [64,256] @ [256,3] + sigmoid ----
    if (tid < BR * 3) {
        const int r = tid / 3;
        const int c = tid - 3 * r;
        float z = 0.0f;
        for (int kb = 0; kb < 32; ++kb) {
            const s16x8 hv = *reinterpret_cast<const s16x8*>(
                sAb + r * 512 + (((unsigned)(kb * 16)) ^ ((unsigned)((r & 7) << 4))));
            #pragma unroll
            for (int j = 0; j < 8; ++j)
                z = fmaf(bf2f((unsigned short)hv[j]), w4[(kb * 8 + j) * 3 + c], z);
        }
        z += b4[c];
        const int pi = p0 + r;
        if (pi < N) out[pi * 3 + c] = 1.0f / (1.0f + expf(-z));
    }
}

// ---- round-3 fused kernel kept as ws_size fallback (verified passing) ----
template<bool BFT>
__global__ __launch_bounds__(NTHREADS, 3)
void fused_hashmlp(const float* __restrict__ x, const float* __restrict__ table,
                   const unsigned short* __restrict__ tbf,
                   const unsigned short* __restrict__ wt,
                   const float* __restrict__ b1, const float* __restrict__ b2,
                   const float* __restrict__ b3,
                   const float* __restrict__ w4, const float* __restrict__ b4,
                   float* __restrict__ out, int N)
{
    __shared__ float sX[BR][3];
    __shared__ unsigned short sA[BR * 256];
    const int tid = threadIdx.x;
    const int p0  = blockIdx.x * BR;
    if (p0 >= N) return;
    char* sAb = (char*)sA;

    if (tid < BR * 3) sX[tid / 3][tid % 3] = x[p0 * 3 + tid];
    __syncthreads();

    #pragma unroll
    for (int it = 0; it < 4; ++it) {
        const int task = it * NTHREADS + tid;
        const int l = task >> 6;
        const int p = task & 63;
        const float sc  = c_scale[l];
        const float inv = (1.0f / 1.5f);
        const float px = sX[p][0] * inv * sc + 0.5f;
        const float py = sX[p][1] * inv * sc + 0.5f;
        const float pz = sX[p][2] * inv * sc + 0.5f;
        const float fx = floorf(px), fy = floorf(py), fz = floorf(pz);
        const float rx = px - fx, ry = py - fy, rz = pz - fz;
        const unsigned ux = (unsigned)fx, uy = (unsigned)fy, uz = (unsigned)fz;
        const unsigned off = c_off[l];
        const unsigned r1  = c_res1[l];
        const bool dense = (l < 5);
        float ax = 0.0f, ay = 0.0f;
        #pragma unroll
        for (int c = 0; c < 8; ++c) {
            const unsigned bx = c & 1, by = (c >> 1) & 1, bz = (c >> 2) & 1;
            const unsigned cx = ux + bx, cy = uy + by, cz = uz + bz;
            const float wx = bx ? rx : (1.0f - rx);
            const float wy = by ? ry : (1.0f - ry);
            const float wz = bz ? rz : (1.0f - rz);
            const float w = wx * wy * wz;
            unsigned idx;
            if (dense) idx = cx + cy * r1 + cz * r1 * r1;
            else       idx = (cx ^ (cy * 2654435761u) ^ (cz * 805459861u)) & 524287u;
            float tx, ty;
            if (BFT) {
                const unsigned v = *reinterpret_cast<const unsigned*>(tbf + 2u * (idx + off));
                tx = bf2f((unsigned short)(v & 0xFFFFu));
                ty = bf2f((unsigned short)(v >> 16));
            } else {
                const float2 tv = *reinterpret_cast<const float2*>(table + 2u * (idx + off));
                tx = tv.x; ty = tv.y;
            }
            ax = fmaf(w, tx, ax);
            ay = fmaf(w, ty, ay);
        }
        const unsigned pack = (unsigned)f2bf(ax) | ((unsigned)f2bf(ay) << 16);
        *reinterpret_cast<unsigned*>(sAb + p * 512 + ((l * 4) ^ ((p & 7) << 4))) = pack;
    }
    __syncthreads();

    const int lane = tid & 63;
    const int wid  = tid >> 6;
    const int rowb = wid * 64;
    const int arow = lane & 15;
    const int kgrp = lane >> 4;
    const int bcol = lane & 15;

    f32x4 acc[4][4];

    auto epilogue = [&](const float* __restrict__ bias) {
        #pragma unroll
        for (int rt = 0; rt < 4; ++rt) {
            const int f0 = rowb + rt * 16 + kgrp * 4;
            const float4 bv = *reinterpret_cast<const float4*>(bias + f0);
            #pragma unroll
            for (int ct = 0; ct < 4; ++ct) {
                const int p = ct * 16 + bcol;
                const float v0 = fmaxf(acc[rt][ct][0] + bv.x, 0.0f);
                const float v1 = fmaxf(acc[rt][ct][1] + bv.y, 0.0f);
                const float v2 = fmaxf(acc[rt][ct][2] + bv.z, 0.0f);
                const float v3 = fmaxf(acc[rt][ct][3] + bv.w, 0.0f);
                uint2 pk;
                pk.x = (unsigned)f2bf(v0) | ((unsigned)f2bf(v1) << 16);
                pk.y = (unsigned)f2bf(v2) | ((unsigned)f2bf(v3) << 16);
                *reinterpret_cast<uint2*>(
                    sAb + p * 512 + (((unsigned)(2 * f0)) ^ ((unsigned)((p & 7) << 4)))) = pk;
            }
        }
    };

    {
        #pragma unroll
        for (int rt = 0; rt < 4; ++rt)
            #pragma unroll
            for (int ct = 0; ct < 4; ++ct) acc[rt][ct] = f32x4{0.f, 0.f, 0.f, 0.f};
        s16x8 wfr[4];
        #pragma unroll
        for (int rt = 0; rt < 4; ++rt)
            wfr[rt] = *reinterpret_cast<const s16x8*>(wt + (rowb + rt * 16 + arow) * 32 + kgrp * 8);
        #pragma unroll
        for (int ct = 0; ct < 4; ++ct) {
            const int p = ct * 16 + bcol;
            const s16x8 bfr = *reinterpret_cast<const s16x8*>(
                sAb + p * 512 + (((unsigned)(kgrp * 16)) ^ ((unsigned)((p & 7) << 4))));
            #pragma unroll
            for (int rt = 0; rt < 4; ++rt)
                acc[rt][ct] = mfma_bf16(wfr[rt], bfr, acc[rt][ct]);
        }
        __syncthreads();
        epilogue(b1);
        __syncthreads();
    }

    #pragma unroll 1
    for (int layer = 0; layer < 2; ++layer) {
        const unsigned short* __restrict__ W = wt + 8192 + (layer << 16);
        #pragma unroll
        for (int rt = 0; rt < 4; ++rt)
            #pragma unroll
            for (int ct = 0; ct < 4; ++ct) acc[rt][ct] = f32x4{0.f, 0.f, 0.f, 0.f};
        for (int ks = 0; ks < 8; ++ks) {
            s16x8 wfr[4];
            #pragma unroll
            for (int rt = 0; rt < 4; ++rt)
                wfr[rt] = *reinterpret_cast<const s16x8*>(
                    W + (rowb + rt * 16 + arow) * 256 + ks * 32 + kgrp * 8);
            #pragma unroll
            for (int ct = 0; ct < 4; ++ct) {
                const int p = ct * 16 + bcol;
                const s16x8 bfr = *reinterpret_cast<const s16x8*>(
                    sAb + p * 512 + (((unsigned)(ks * 64 + kgrp * 16)) ^ ((unsigned)((p & 7) << 4))));
                #pragma unroll
                for (int rt = 0; rt < 4; ++rt)
                    acc[rt][ct] = mfma_bf16(wfr[rt], bfr, acc[rt][ct]);
            }
        }
        __syncthreads();
        epilogue(layer == 0 ? b2 : b3);
        __syncthreads();
    }

    if (tid < BR * 3) {
        const int r = tid / 3;
        const int c = tid - 3 * r;
        float z = 0.0f;
        for (int kb = 0; kb < 32; ++kb) {
            const s16x8 hv = *reinterpret_cast<const s16x8*>(
                sAb + r * 512 + (((unsigned)(kb * 16)) ^ ((unsigned)((r & 7) << 4))));
            #pragma unroll
            for (int j = 0; j < 8; ++j)
                z = fmaf(bf2f((unsigned short)hv[j]), w4[(kb * 8 + j) * 3 + c], z);
        }
        z += b4[c];
        const int pi = p0 + r;
        if (pi < N) out[pi * 3 + c] = 1.0f / (1.0f + expf(-z));
    }
}

extern "C" void kernel_launch(void* const* d_in, const int* in_sizes, int n_in,
                              void* d_out, int out_size, void* d_ws, size_t ws_size,
                              hipStream_t stream) {
    const float* x     = (const float*)d_in[0];
    const float* table = (const float*)d_in[1];
    const float* w1    = (const float*)d_in[2];
    const float* b1    = (const float*)d_in[3];
    const float* w2    = (const float*)d_in[4];
    const float* b2    = (const float*)d_in[5];
    const float* w3    = (const float*)d_in[6];
    const float* b3    = (const float*)d_in[7];
    const float* w4    = (const float*)d_in[8];
    const float* b4    = (const float*)d_in[9];
    float* out = (float*)d_out;

    const int N = in_sizes[0] / 3;

    const size_t W_ELEMS    = 139264;                   // bf16 weight elements
    const size_t TBL_ELEMS  = 12239728;                 // 2 * TOTAL bf16 table elements
    const size_t need_bf    = (W_ELEMS + TBL_ELEMS) * 2;   // 24.76 MB
    const size_t FEAT_BYTES = (size_t)N * 64;              // uint2[8][N]
    const size_t need_split = need_bf + FEAT_BYTES;        // ~58.3 MB

    unsigned short* wsw = (unsigned short*)d_ws;
    unsigned short* tbf = wsw + W_ELEMS;
    uint2* feat2 = (uint2*)((char*)d_ws + need_bf);     // 8B-aligned (need_bf % 8 == 0)

    hipLaunchKernelGGL(convert_w, dim3(544), dim3(256), 0, stream, w1, w2, w3, wsw);

    if (ws_size >= need_split) {
        const size_t n4 = TBL_ELEMS / 4;
        hipLaunchKernelGGL(convert_table, dim3((unsigned)((n4 + 255) / 256)), dim3(256), 0, stream,
                           table, tbf, (int)n4);
        hipLaunchKernelGGL(encode_kernel, dim3((N + 255) / 256, 8), dim3(256), 0, stream,
                           x, tbf, feat2, N);
        hipLaunchKernelGGL(mlp_kernel, dim3((N + BR - 1) / BR), dim3(NTHREADS), 0, stream,
                           feat2, wsw, b1, b2, b3, w4, b4, out, N);
    } else if (ws_size >= need_bf) {
        const size_t n4 = TBL_ELEMS / 4;
        hipLaunchKernelGGL(convert_table, dim3((unsigned)((n4 + 255) / 256)), dim3(256), 0, stream,
                           table, tbf, (int)n4);
        hipLaunchKernelGGL(fused_hashmlp<true>, dim3((N + BR - 1) / BR), dim3(NTHREADS), 0, stream,
                           x, table, tbf, wsw, b1, b2, b3, w4, b4, out, N);
    } else {
        hipLaunchKernelGGL(fused_hashmlp<false>, dim3((N + BR - 1) / BR), dim3(NTHREADS), 0, stream,
                           x, table, tbf, wsw, b1, b2, b3, w4, b4, out, N);
    }
}

// Round 8
// 643.270 us; speedup vs baseline: 1.4126x; 1.0335x over previous
//
#include <hip/hip_runtime.h>
#include <hip/hip_bf16.h>
#include <math.h>

#define NTHREADS 256
#define BR 64

typedef __attribute__((ext_vector_type(8))) short   s16x8;
typedef __attribute__((ext_vector_type(8))) __bf16  bf16x8;
typedef __attribute__((ext_vector_type(4))) float   f32x4;

// ---- Compile-time hash-grid constants (verified exact: absmax 0.0 rounds 1,3,4,6,7) ----
__device__ __constant__ float c_scale[16] = {
    15.0f,        21.110607f,  29.554930f,  41.224254f,
    57.350239f,   79.634946f,  110.430473f, 152.987205f,
    211.796890f,  293.066769f, 405.374657f, 560.574388f,
    775.046906f,  1071.429232f, 1481.003616f, 2047.0f
};
__device__ __constant__ unsigned c_off[16] = {
    0u,        4920u,     18744u,    51512u,
    136696u,   352696u,   876984u,   1401272u,
    1925560u,  2449848u,  2974136u,  3498424u,
    4022712u,  4547000u,  5071288u,  5595576u
};
__device__ __constant__ unsigned c_res1[16] = {
    17u, 24u, 32u, 44u, 60u, 0u,0u,0u,0u,0u,0u,0u,0u,0u,0u,0u
};

__device__ inline unsigned short f2bf(float f) {
    unsigned u = __builtin_bit_cast(unsigned, f);
    u += 0x7FFFu + ((u >> 16) & 1u);          // round-to-nearest-even
    return (unsigned short)(u >> 16);
}
__device__ inline float bf2f(unsigned short h) {
    unsigned u = ((unsigned)h) << 16;
    return __builtin_bit_cast(float, u);
}
// HW packed f32->bf16 RNE convert (T12 primitive; same rounding as f2bf)
__device__ inline unsigned cvtpk(float lo, float hi) {
    unsigned r;
    asm("v_cvt_pk_bf16_f32 %0, %1, %2" : "=v"(r) : "v"(lo), "v"(hi));
    return r;
}
__device__ inline f32x4 mfma_bf16(s16x8 a, s16x8 b, f32x4 c) {
    return __builtin_amdgcn_mfma_f32_16x16x32_bf16(
        __builtin_bit_cast(bf16x8, a), __builtin_bit_cast(bf16x8, b), c, 0, 0, 0);
}

// ws layout (bf16 elems): wt1[256][32]@0 ; wt2[256][256]@8192 ; wt3[256][256]@73728 ;
// w4t[16][256]@139264 (rows 3-15 zero) ; bf16 table @143360 ; feat2 uint2[8][N] after.
__global__ void convert_w(const float* __restrict__ w1, const float* __restrict__ w2,
                          const float* __restrict__ w3, const float* __restrict__ w4,
                          unsigned short* __restrict__ ws) {
    int t = blockIdx.x * blockDim.x + threadIdx.x;
    if (t < 8192) {
        int col = t >> 5, k = t & 31;
        ws[t] = f2bf(w1[k * 256 + col]);
    } else if (t < 73728) {
        int u = t - 8192; int col = u >> 8, k = u & 255;
        ws[t] = f2bf(w2[k * 256 + col]);
    } else if (t < 139264) {
        int u = t - 73728; int col = u >> 8, k = u & 255;
        ws[t] = f2bf(w3[k * 256 + col]);
    } else if (t < 143360) {
        int u = t - 139264; int ch = u >> 8, k = u & 255;
        ws[t] = (ch < 3) ? f2bf(w4[k * 3 + ch]) : (unsigned short)0;
    }
}

__global__ void convert_table(const float* __restrict__ t, unsigned short* __restrict__ o, int n4) {
    int i = blockIdx.x * blockDim.x + threadIdx.x;
    if (i < n4) {
        float4 v = ((const float4*)t)[i];
        ushort4 r;
        r.x = f2bf(v.x); r.y = f2bf(v.y); r.z = f2bf(v.z); r.w = f2bf(v.w);
        ((ushort4*)o)[i] = r;
    }
}

// ---- encode: XCD-pinned level-pairs. lp = blockIdx.x & 7: consecutive blocks
// round-robin XCDs, so XCD k gathers ONLY level-pair k -> per-XCD working set
// 0.08-4 MB fits its private 4 MB L2 (vs all-XCDs-touch-24.5MB before). ----
__global__ __launch_bounds__(256)
void encode_kernel(const float* __restrict__ x, const unsigned short* __restrict__ tbf,
                   uint2* __restrict__ feat2, int N)
{
    const int lp = blockIdx.x & 7;             // XCD-pinned, wave-uniform
    const int p  = (blockIdx.x >> 3) * 256 + threadIdx.x;
    if (p >= N) return;

    const float inv = (1.0f / 1.5f);
    const float xc = x[3 * p + 0] * inv;
    const float yc = x[3 * p + 1] * inv;
    const float zc = x[3 * p + 2] * inv;

    unsigned outv[2];
    #pragma unroll
    for (int s = 0; s < 2; ++s) {
        const int l = lp * 2 + s;              // uniform
        const float sc = c_scale[l];
        const float px = xc * sc + 0.5f;
        const float py = yc * sc + 0.5f;
        const float pz = zc * sc + 0.5f;
        const float fx = floorf(px), fy = floorf(py), fz = floorf(pz);
        const float rx = px - fx, ry = py - fy, rz = pz - fz;
        const unsigned ux = (unsigned)fx, uy = (unsigned)fy, uz = (unsigned)fz;
        const unsigned off = c_off[l];
        const unsigned r1  = c_res1[l];
        const bool dense = (l < 5);            // uniform
        float ax = 0.0f, ay = 0.0f;
        #pragma unroll
        for (int c = 0; c < 8; ++c) {
            const unsigned bx = c & 1, by = (c >> 1) & 1, bz = (c >> 2) & 1;
            const unsigned cx = ux + bx, cy = uy + by, cz = uz + bz;
            const float wx = bx ? rx : (1.0f - rx);
            const float wy = by ? ry : (1.0f - ry);
            const float wz = bz ? rz : (1.0f - rz);
            const float w = wx * wy * wz;
            unsigned idx;
            if (dense) idx = cx + cy * r1 + cz * r1 * r1;
            else       idx = (cx ^ (cy * 2654435761u) ^ (cz * 805459861u)) & 524287u;
            const unsigned v = *reinterpret_cast<const unsigned*>(tbf + 2u * (idx + off));
            ax = fmaf(w, bf2f((unsigned short)(v & 0xFFFFu)), ax);
            ay = fmaf(w, bf2f((unsigned short)(v >> 16)), ay);
        }
        outv[s] = cvtpk(ax, ay);
    }
    feat2[(size_t)lp * N + p] = make_uint2(outv[0], outv[1]);   // 512B/wave coalesced
}

// ---- MLP (transposed operands): A = weights wt[o][k], B = activations sA[p][k].
// Epilogue: packed ds_write_b64 + v_cvt_pk_bf16_f32 (2 vals/instr vs ~10-op manual RNE).
// Layer 4 via MFMA vs w4t (rows 3-15 zero) -> kills 256-deep serial FMA chain.
// __launch_bounds__(256,3): 170-reg budget, no spill (round-4 lesson: (256,4) spills).
__global__ __launch_bounds__(NTHREADS, 3)
void mlp_kernel(const uint2* __restrict__ feat2,
                const unsigned short* __restrict__ wt,
                const float* __restrict__ b1, const float* __restrict__ b2,
                const float* __restrict__ b3, const float* __restrict__ b4,
                float* __restrict__ out, int N)
{
    __shared__ unsigned short sA[BR * 256];   // 32 KB, rows of 512B, XOR-swizzled
    char* sAb = (char*)sA;

    const int tid = threadIdx.x;
    const int p0  = blockIdx.x * BR;
    if (p0 >= N) return;

    // ---- A-tile load: 512 uint2 (8 planes x 64 points), coalesced reads ----
    #pragma unroll
    for (int it = 0; it < 2; ++it) {
        const int t  = it * NTHREADS + tid;
        const int lp = t >> 6;                 // plane 0..7
        const int p  = t & 63;
        const uint2 v = feat2[(size_t)lp * N + p0 + p];
        *reinterpret_cast<uint2*>(
            sAb + p * 512 + (((unsigned)(lp * 8)) ^ ((unsigned)((p & 7) << 4)))) = v;
    }
    __syncthreads();

    const int lane = tid & 63;
    const int wid  = tid >> 6;
    const int rowb = wid * 64;           // wave's 64-FEATURE slice (output rows)
    const int arow = lane & 15;          // A-frag row  = output feature (within 16)
    const int kgrp = lane >> 4;          // k-offset group (k0 = kgrp*8)
    const int bcol = lane & 15;          // B-frag col   = point (within 16)

    f32x4 acc[4][4];                     // [feature-tile rt][point-tile ct]

    auto epilogue = [&](const float* __restrict__ bias) {
        #pragma unroll
        for (int rt = 0; rt < 4; ++rt) {
            const int f0 = rowb + rt * 16 + kgrp * 4;       // 4 consecutive features
            const float4 bv = *reinterpret_cast<const float4*>(bias + f0);
            #pragma unroll
            for (int ct = 0; ct < 4; ++ct) {
                const int p = ct * 16 + bcol;
                const float v0 = fmaxf(acc[rt][ct][0] + bv.x, 0.0f);
                const float v1 = fmaxf(acc[rt][ct][1] + bv.y, 0.0f);
                const float v2 = fmaxf(acc[rt][ct][2] + bv.z, 0.0f);
                const float v3 = fmaxf(acc[rt][ct][3] + bv.w, 0.0f);
                uint2 pk;
                pk.x = cvtpk(v0, v1);
                pk.y = cvtpk(v2, v3);
                *reinterpret_cast<uint2*>(
                    sAb + p * 512 + (((unsigned)(2 * f0)) ^ ((unsigned)((p & 7) << 4)))) = pk;
            }
        }
    };

    // ---- layer 1: K=32, single MFMA per (rt,ct) ----
    {
        #pragma unroll
        for (int rt = 0; rt < 4; ++rt)
            #pragma unroll
            for (int ct = 0; ct < 4; ++ct) acc[rt][ct] = f32x4{0.f, 0.f, 0.f, 0.f};

        s16x8 wfr[4];
        #pragma unroll
        for (int rt = 0; rt < 4; ++rt)
            wfr[rt] = *reinterpret_cast<const s16x8*>(wt + (rowb + rt * 16 + arow) * 32 + kgrp * 8);
        #pragma unroll
        for (int ct = 0; ct < 4; ++ct) {
            const int p = ct * 16 + bcol;
            const s16x8 bfr = *reinterpret_cast<const s16x8*>(
                sAb + p * 512 + (((unsigned)(kgrp * 16)) ^ ((unsigned)((p & 7) << 4))));
            #pragma unroll
            for (int rt = 0; rt < 4; ++rt)
                acc[rt][ct] = mfma_bf16(wfr[rt], bfr, acc[rt][ct]);
        }
        __syncthreads();
        epilogue(b1);
        __syncthreads();
    }

    // ---- layers 2 & 3: K=256 ----
    #pragma unroll 1
    for (int layer = 0; layer < 2; ++layer) {
        const unsigned short* __restrict__ W = wt + 8192 + (layer << 16);
        #pragma unroll
        for (int rt = 0; rt < 4; ++rt)
            #pragma unroll
            for (int ct = 0; ct < 4; ++ct) acc[rt][ct] = f32x4{0.f, 0.f, 0.f, 0.f};

        for (int ks = 0; ks < 8; ++ks) {
            s16x8 wfr[4];
            #pragma unroll
            for (int rt = 0; rt < 4; ++rt)
                wfr[rt] = *reinterpret_cast<const s16x8*>(
                    W + (rowb + rt * 16 + arow) * 256 + ks * 32 + kgrp * 8);
            #pragma unroll
            for (int ct = 0; ct < 4; ++ct) {
                const int p = ct * 16 + bcol;
                const s16x8 bfr = *reinterpret_cast<const s16x8*>(
                    sAb + p * 512 + (((unsigned)(ks * 64 + kgrp * 16)) ^ ((unsigned)((p & 7) << 4))));
                #pragma unroll
                for (int rt = 0; rt < 4; ++rt)
                    acc[rt][ct] = mfma_bf16(wfr[rt], bfr, acc[rt][ct]);
            }
        }
        __syncthreads();
        epilogue(layer == 0 ? b2 : b3);
        __syncthreads();
    }

    // ---- layer 4 via MFMA: A = w4t[16][256] (rows 3-15 zero), B = this wave's 16 points ----
    {
        const unsigned short* __restrict__ W4 = wt + 139264;
        const int p = wid * 16 + bcol;        // this wave's point
        f32x4 a4 = f32x4{0.f, 0.f, 0.f, 0.f};
        #pragma unroll
        for (int ks = 0; ks < 8; ++ks) {
            const s16x8 wfr = *reinterpret_cast<const s16x8*>(W4 + arow * 256 + ks * 32 + kgrp * 8);
            const s16x8 bfr = *reinterpret_cast<const s16x8*>(
                sAb + p * 512 + (((unsigned)(ks * 64 + kgrp * 16)) ^ ((unsigned)((p & 7) << 4))));
            a4 = mfma_bf16(wfr, bfr, a4);
        }
        // D row = kgrp*4 + r, col = bcol -> channels 0-2 live in kgrp==0 lanes, regs 0-2
        if (kgrp == 0) {
            const int pi = p0 + p;
            if (pi < N) {
                #pragma unroll
                for (int c = 0; c < 3; ++c) {
                    const float z = a4[c] + b4[c];
                    out[pi * 3 + c] = 1.0f / (1.0f + expf(-z));
                }
            }
        }
    }
}

// ---- fused fallback (fp32 table, weights in ws) — only if ws can't hold table+feat ----
__global__ __launch_bounds__(NTHREADS, 3)
void fused_hashmlp(const float* __restrict__ x, const float* __restrict__ table,
                   const unsigned short* __restrict__ wt,
                   const float* __restrict__ b1, const float* __restrict__ b2,
                   const float* __restrict__ b3,
                   const float* __restrict__ w4, const float* __restrict__ b4,
                   float* __restrict__ out, int N)
{
    __shared__ float sX[BR][3];
    __shared__ unsigned short sA[BR * 256];
    const int tid = threadIdx.x;
    const int p0  = blockIdx.x * BR;
    if (p0 >= N) return;
    char* sAb = (char*)sA;

    if (tid < BR * 3) sX[tid / 3][tid % 3] = x[p0 * 3 + tid];
    __syncthreads();

    #pragma unroll
    for (int it = 0; it < 4; ++it) {
        const int task = it * NTHREADS + tid;
        const int l = task >> 6;
        const int p = task & 63;
        const float sc  = c_scale[l];
        const float inv = (1.0f / 1.5f);
        const float px = sX[p][0] * inv * sc + 0.5f;
        const float py = sX[p][1] * inv * sc + 0.5f;
        const float pz = sX[p][2] * inv * sc + 0.5f;
        const float fx = floorf(px), fy = floorf(py), fz = floorf(pz);
        const float rx = px - fx, ry = py - fy, rz = pz - fz;
        const unsigned ux = (unsigned)fx, uy = (unsigned)fy, uz = (unsigned)fz;
        const unsigned off = c_off[l];
        const unsigned r1  = c_res1[l];
        const bool dense = (l < 5);
        float ax = 0.0f, ay = 0.0f;
        #pragma unroll
        for (int c = 0; c < 8; ++c) {
            const unsigned bx = c & 1, by = (c >> 1) & 1, bz = (c >> 2) & 1;
            const unsigned cx = ux + bx, cy = uy + by, cz = uz + bz;
            const float wx = bx ? rx : (1.0f - rx);
            const float wy = by ? ry : (1.0f - ry);
            const float wz = bz ? rz : (1.0f - rz);
            const float w = wx * wy * wz;
            unsigned idx;
            if (dense) idx = cx + cy * r1 + cz * r1 * r1;
            else       idx = (cx ^ (cy * 2654435761u) ^ (cz * 805459861u)) & 524287u;
            const float2 tv = *reinterpret_cast<const float2*>(table + 2u * (idx + off));
            ax = fmaf(w, tv.x, ax);
            ay = fmaf(w, tv.y, ay);
        }
        const unsigned pack = (unsigned)f2bf(ax) | ((unsigned)f2bf(ay) << 16);
        *reinterpret_cast<unsigned*>(sAb + p * 512 + ((l * 4) ^ ((p & 7) << 4))) = pack;
    }
    __syncthreads();

    const int lane = tid & 63;
    const int wid  = tid >> 6;
    const int rowb = wid * 64;
    const int arow = lane & 15;
    const int kgrp = lane >> 4;
    const int bcol = lane & 15;

    f32x4 acc[4][4];

    auto epilogue = [&](const float* __restrict__ bias) {
        #pragma unroll
        for (int rt = 0; rt < 4; ++rt) {
            const int f0 = rowb + rt * 16 + kgrp * 4;
            const float4 bv = *reinterpret_cast<const float4*>(bias + f0);
            #pragma unroll
            for (int ct = 0; ct < 4; ++ct) {
                const int p = ct * 16 + bcol;
                const float v0 = fmaxf(acc[rt][ct][0] + bv.x, 0.0f);
                const float v1 = fmaxf(acc[rt][ct][1] + bv.y, 0.0f);
                const float v2 = fmaxf(acc[rt][ct][2] + bv.z, 0.0f);
                const float v3 = fmaxf(acc[rt][ct][3] + bv.w, 0.0f);
                uint2 pk;
                pk.x = (unsigned)f2bf(v0) | ((unsigned)f2bf(v1) << 16);
                pk.y = (unsigned)f2bf(v2) | ((unsigned)f2bf(v3) << 16);
                *reinterpret_cast<uint2*>(
                    sAb + p * 512 + (((unsigned)(2 * f0)) ^ ((unsigned)((p & 7) << 4)))) = pk;
            }
        }
    };

    {
        #pragma unroll
        for (int rt = 0; rt < 4; ++rt)
            #pragma unroll
            for (int ct = 0; ct < 4; ++ct) acc[rt][ct] = f32x4{0.f, 0.f, 0.f, 0.f};
        s16x8 wfr[4];
        #pragma unroll
        for (int rt = 0; rt < 4; ++rt)
            wfr[rt] = *reinterpret_cast<const s16x8*>(wt + (rowb + rt * 16 + arow) * 32 + kgrp * 8);
        #pragma unroll
        for (int ct = 0; ct < 4; ++ct) {
            const int p = ct * 16 + bcol;
            const s16x8 bfr = *reinterpret_cast<const s16x8*>(
                sAb + p * 512 + (((unsigned)(kgrp * 16)) ^ ((unsigned)((p & 7) << 4))));
            #pragma unroll
            for (int rt = 0; rt < 4; ++rt)
                acc[rt][ct] = mfma_bf16(wfr[rt], bfr, acc[rt][ct]);
        }
        __syncthreads();
        epilogue(b1);
        __syncthreads();
    }

    #pragma unroll 1
    for (int layer = 0; layer < 2; ++layer) {
        const unsigned short* __restrict__ W = wt + 8192 + (layer << 16);
        #pragma unroll
        for (int rt = 0; rt < 4; ++rt)
            #pragma unroll
            for (int ct = 0; ct < 4; ++ct) acc[rt][ct] = f32x4{0.f, 0.f, 0.f, 0.f};
        for (int ks = 0; ks < 8; ++ks) {
            s16x8 wfr[4];
            #pragma unroll
            for (int rt = 0; rt < 4; ++rt)
                wfr[rt] = *reinterpret_cast<const s16x8*>(
                    W + (rowb + rt * 16 + arow) * 256 + ks * 32 + kgrp * 8);
            #pragma unroll
            for (int ct = 0; ct < 4; ++ct) {
                const int p = ct * 16 + bcol;
                const s16x8 bfr = *reinterpret_cast<const s16x8*>(
                    sAb + p * 512 + (((unsigned)(ks * 64 + kgrp * 16)) ^ ((unsigned)((p & 7) << 4))));
                #pragma unroll
                for (int rt = 0; rt < 4; ++rt)
                    acc[rt][ct] = mfma_bf16(wfr[rt], bfr, acc[rt][ct]);
            }
        }
        __syncthreads();
        epilogue(layer == 0 ? b2 : b3);
        __syncthreads();
    }

    if (tid < BR * 3) {
        const int r = tid / 3;
        const int c = tid - 3 * r;
        float z0 = 0.0f, z1 = 0.0f;
        for (int kb = 0; kb < 32; kb += 2) {
            const s16x8 hv0 = *reinterpret_cast<const s16x8*>(
                sAb + r * 512 + (((unsigned)(kb * 16)) ^ ((unsigned)((r & 7) << 4))));
            const s16x8 hv1 = *reinterpret_cast<const s16x8*>(
                sAb + r * 512 + (((unsigned)((kb + 1) * 16)) ^ ((unsigned)((r & 7) << 4))));
            #pragma unroll
            for (int j = 0; j < 8; ++j) {
                z0 = fmaf(bf2f((unsigned short)hv0[j]), w4[(kb * 8 + j) * 3 + c], z0);
                z1 = fmaf(bf2f((unsigned short)hv1[j]), w4[((kb + 1) * 8 + j) * 3 + c], z1);
            }
        }
        const float z = z0 + z1 + b4[c];
        const int pi = p0 + r;
        if (pi < N) out[pi * 3 + c] = 1.0f / (1.0f + expf(-z));
    }
}

extern "C" void kernel_launch(void* const* d_in, const int* in_sizes, int n_in,
                              void* d_out, int out_size, void* d_ws, size_t ws_size,
                              hipStream_t stream) {
    const float* x     = (const float*)d_in[0];
    const float* table = (const float*)d_in[1];
    const float* w1    = (const float*)d_in[2];
    const float* b1    = (const float*)d_in[3];
    const float* w2    = (const float*)d_in[4];
    const float* b2    = (const float*)d_in[5];
    const float* w3    = (const float*)d_in[6];
    const float* b3    = (const float*)d_in[7];
    const float* w4    = (const float*)d_in[8];
    const float* b4    = (const float*)d_in[9];
    float* out = (float*)d_out;

    const int N = in_sizes[0] / 3;

    const size_t W_ELEMS    = 143360;                   // bf16 weight elems (incl w4t[16][256])
    const size_t TBL_ELEMS  = 12239728;                 // 2 * TOTAL bf16 table elements
    const size_t need_bf    = (W_ELEMS + TBL_ELEMS) * 2;   // 24.77 MB
    const size_t FEAT_BYTES = (size_t)N * 64;              // uint2[8][N]
    const size_t need_split = need_bf + FEAT_BYTES;        // ~58.3 MB

    unsigned short* wsw = (unsigned short*)d_ws;
    unsigned short* tbf = wsw + W_ELEMS;
    uint2* feat2 = (uint2*)((char*)d_ws + need_bf);     // 8B-aligned

    hipLaunchKernelGGL(convert_w, dim3(560), dim3(256), 0, stream, w1, w2, w3, w4, wsw);

    if (ws_size >= need_split) {
        const size_t n4 = TBL_ELEMS / 4;
        hipLaunchKernelGGL(convert_table, dim3((unsigned)((n4 + 255) / 256)), dim3(256), 0, stream,
                           table, tbf, (int)n4);
        const unsigned pblocks = (unsigned)((N + 255) / 256);
        hipLaunchKernelGGL(encode_kernel, dim3(pblocks * 8), dim3(256), 0, stream,
                           x, tbf, feat2, N);
        hipLaunchKernelGGL(mlp_kernel, dim3((N + BR - 1) / BR), dim3(NTHREADS), 0, stream,
                           feat2, wsw, b1, b2, b3, b4, out, N);
    } else {
        hipLaunchKernelGGL(fused_hashmlp, dim3((N + BR - 1) / BR), dim3(NTHREADS), 0, stream,
                           x, table, wsw, b1, b2, b3, w4, b4, out, N);
    }
}

// Round 9
// 611.135 us; speedup vs baseline: 1.4868x; 1.0526x over previous
//
#include <hip/hip_runtime.h>
#include <hip/hip_bf16.h>
#include <math.h>

#define NTHREADS 256
#define BR 64

typedef __attribute__((ext_vector_type(8))) short   s16x8;
typedef __attribute__((ext_vector_type(8))) __bf16  bf16x8;
typedef __attribute__((ext_vector_type(4))) float   f32x4;

// ---- Compile-time hash-grid constants (verified exact: absmax 0.0 rounds 1,3,4,6,7,8) ----
__device__ __constant__ float c_scale[16] = {
    15.0f,        21.110607f,  29.554930f,  41.224254f,
    57.350239f,   79.634946f,  110.430473f, 152.987205f,
    211.796890f,  293.066769f, 405.374657f, 560.574388f,
    775.046906f,  1071.429232f, 1481.003616f, 2047.0f
};
__device__ __constant__ unsigned c_off[16] = {
    0u,        4920u,     18744u,    51512u,
    136696u,   352696u,   876984u,   1401272u,
    1925560u,  2449848u,  2974136u,  3498424u,
    4022712u,  4547000u,  5071288u,  5595576u
};
__device__ __constant__ unsigned c_res1[16] = {
    17u, 24u, 32u, 44u, 60u, 0u,0u,0u,0u,0u,0u,0u,0u,0u,0u,0u
};

__device__ inline unsigned short f2bf(float f) {
    unsigned u = __builtin_bit_cast(unsigned, f);
    u += 0x7FFFu + ((u >> 16) & 1u);          // round-to-nearest-even
    return (unsigned short)(u >> 16);
}
__device__ inline float bf2f(unsigned short h) {
    unsigned u = ((unsigned)h) << 16;
    return __builtin_bit_cast(float, u);
}
// HW packed f32->bf16 RNE convert (T12 primitive; same rounding as f2bf — verified r8 absmax 0.0)
__device__ inline unsigned cvtpk(float lo, float hi) {
    unsigned r;
    asm("v_cvt_pk_bf16_f32 %0, %1, %2" : "=v"(r) : "v"(lo), "v"(hi));
    return r;
}
__device__ inline f32x4 mfma_bf16(s16x8 a, s16x8 b, f32x4 c) {
    return __builtin_amdgcn_mfma_f32_16x16x32_bf16(
        __builtin_bit_cast(bf16x8, a), __builtin_bit_cast(bf16x8, b), c, 0, 0, 0);
}

// ws layout (bf16 elems): wt1[256][32]@0 ; wt2[256][256]@8192 ; wt3[256][256]@73728 ;
// w4t[16][256]@139264 (rows 3-15 zero) ; bf16 table @143360 ; feat2 uint2[8][N] after.
__global__ void convert_w(const float* __restrict__ w1, const float* __restrict__ w2,
                          const float* __restrict__ w3, const float* __restrict__ w4,
                          unsigned short* __restrict__ ws) {
    int t = blockIdx.x * blockDim.x + threadIdx.x;
    if (t < 8192) {
        int col = t >> 5, k = t & 31;
        ws[t] = f2bf(w1[k * 256 + col]);
    } else if (t < 73728) {
        int u = t - 8192; int col = u >> 8, k = u & 255;
        ws[t] = f2bf(w2[k * 256 + col]);
    } else if (t < 139264) {
        int u = t - 73728; int col = u >> 8, k = u & 255;
        ws[t] = f2bf(w3[k * 256 + col]);
    } else if (t < 143360) {
        int u = t - 139264; int ch = u >> 8, k = u & 255;
        ws[t] = (ch < 3) ? f2bf(w4[k * 3 + ch]) : (unsigned short)0;
    }
}

__global__ void convert_table(const float* __restrict__ t, unsigned short* __restrict__ o, int n4) {
    int i = blockIdx.x * blockDim.x + threadIdx.x;
    if (i < n4) {
        float4 v = ((const float4*)t)[i];
        ushort4 r;
        r.x = f2bf(v.x); r.y = f2bf(v.y); r.z = f2bf(v.z); r.w = f2bf(v.w);
        ((ushort4*)o)[i] = r;
    }
}

// ---- encode: 2D grid, lp = blockIdx.y. x-major dispatch => whole chip processes ONE
// level-pair at a time (4 MB footprint <= 32 MB aggregate L2). Round-8's bid&7 XCD-pin
// remap REGRESSED ~50us (all 8 pairs concurrent, mixed L2 working sets) — reverted. ----
__global__ __launch_bounds__(256)
void encode_kernel(const float* __restrict__ x, const unsigned short* __restrict__ tbf,
                   uint2* __restrict__ feat2, int N)
{
    const int p  = blockIdx.x * 256 + threadIdx.x;
    const int lp = blockIdx.y;                 // 0..7, wave-uniform
    if (p >= N) return;

    const float inv = (1.0f / 1.5f);
    const float xc = x[3 * p + 0] * inv;
    const float yc = x[3 * p + 1] * inv;
    const float zc = x[3 * p + 2] * inv;

    unsigned outv[2];
    #pragma unroll
    for (int s = 0; s < 2; ++s) {
        const int l = lp * 2 + s;              // uniform
        const float sc = c_scale[l];
        const float px = xc * sc + 0.5f;
        const float py = yc * sc + 0.5f;
        const float pz = zc * sc + 0.5f;
        const float fx = floorf(px), fy = floorf(py), fz = floorf(pz);
        const float rx = px - fx, ry = py - fy, rz = pz - fz;
        const unsigned ux = (unsigned)fx, uy = (unsigned)fy, uz = (unsigned)fz;
        const unsigned off = c_off[l];
        const unsigned r1  = c_res1[l];
        const bool dense = (l < 5);            // uniform
        float ax = 0.0f, ay = 0.0f;
        #pragma unroll
        for (int c = 0; c < 8; ++c) {
            const unsigned bx = c & 1, by = (c >> 1) & 1, bz = (c >> 2) & 1;
            const unsigned cx = ux + bx, cy = uy + by, cz = uz + bz;
            const float wx = bx ? rx : (1.0f - rx);
            const float wy = by ? ry : (1.0f - ry);
            const float wz = bz ? rz : (1.0f - rz);
            const float w = wx * wy * wz;
            unsigned idx;
            if (dense) idx = cx + cy * r1 + cz * r1 * r1;
            else       idx = (cx ^ (cy * 2654435761u) ^ (cz * 805459861u)) & 524287u;
            const unsigned v = *reinterpret_cast<const unsigned*>(tbf + 2u * (idx + off));
            ax = fmaf(w, bf2f((unsigned short)(v & 0xFFFFu)), ax);
            ay = fmaf(w, bf2f((unsigned short)(v >> 16)), ay);
        }
        outv[s] = cvtpk(ax, ay);
    }
    feat2[(size_t)lp * N + p] = make_uint2(outv[0], outv[1]);   // 512B/wave coalesced
}

// ---- MLP (transposed operands): A = weights wt[o][k], B = activations sA[p][k].
// r9: explicit 2-stage weight prefetch in layers 2&3 (wfr for ks+1 issued before ks's
// MFMA block) + layer-1 wfr hoisted above the staging barrier — hides L2 ~200cyc
// weight-load latency that left mlp 45% idle at r8 (Mfma 21% + VALU 19%).
// __launch_bounds__(256,3): 170-reg budget; arch ~80 + 64 acc fits, no spill.
__global__ __launch_bounds__(NTHREADS, 3)
void mlp_kernel(const uint2* __restrict__ feat2,
                const unsigned short* __restrict__ wt,
                const float* __restrict__ b1, const float* __restrict__ b2,
                const float* __restrict__ b3, const float* __restrict__ b4,
                float* __restrict__ out, int N)
{
    __shared__ unsigned short sA[BR * 256];   // 32 KB, rows of 512B, XOR-swizzled
    char* sAb = (char*)sA;

    const int tid = threadIdx.x;
    const int p0  = blockIdx.x * BR;
    if (p0 >= N) return;

    const int lane = tid & 63;
    const int wid  = tid >> 6;
    const int rowb = wid * 64;           // wave's 64-FEATURE slice (output rows)
    const int arow = lane & 15;          // A-frag row  = output feature (within 16)
    const int kgrp = lane >> 4;          // k-offset group (k0 = kgrp*8)
    const int bcol = lane & 15;          // B-frag col   = point (within 16)

    // ---- layer-1 weight fragments: global, LDS-independent -> issue BEFORE staging
    s16x8 wfr1[4];
    #pragma unroll
    for (int rt = 0; rt < 4; ++rt)
        wfr1[rt] = *reinterpret_cast<const s16x8*>(wt + (rowb + rt * 16 + arow) * 32 + kgrp * 8);

    // ---- A-tile load: 512 uint2 (8 planes x 64 points), coalesced reads ----
    #pragma unroll
    for (int it = 0; it < 2; ++it) {
        const int t  = it * NTHREADS + tid;
        const int lp = t >> 6;                 // plane 0..7
        const int p  = t & 63;
        const uint2 v = feat2[(size_t)lp * N + p0 + p];
        *reinterpret_cast<uint2*>(
            sAb + p * 512 + (((unsigned)(lp * 8)) ^ ((unsigned)((p & 7) << 4)))) = v;
    }
    __syncthreads();

    f32x4 acc[4][4];                     // [feature-tile rt][point-tile ct]

    auto epilogue = [&](const float* __restrict__ bias) {
        #pragma unroll
        for (int rt = 0; rt < 4; ++rt) {
            const int f0 = rowb + rt * 16 + kgrp * 4;       // 4 consecutive features
            const float4 bv = *reinterpret_cast<const float4*>(bias + f0);
            #pragma unroll
            for (int ct = 0; ct < 4; ++ct) {
                const int p = ct * 16 + bcol;
                const float v0 = fmaxf(acc[rt][ct][0] + bv.x, 0.0f);
                const float v1 = fmaxf(acc[rt][ct][1] + bv.y, 0.0f);
                const float v2 = fmaxf(acc[rt][ct][2] + bv.z, 0.0f);
                const float v3 = fmaxf(acc[rt][ct][3] + bv.w, 0.0f);
                uint2 pk;
                pk.x = cvtpk(v0, v1);
                pk.y = cvtpk(v2, v3);
                *reinterpret_cast<uint2*>(
                    sAb + p * 512 + (((unsigned)(2 * f0)) ^ ((unsigned)((p & 7) << 4)))) = pk;
            }
        }
    };

    // ---- layer 1: K=32, single MFMA per (rt,ct) ----
    {
        #pragma unroll
        for (int rt = 0; rt < 4; ++rt)
            #pragma unroll
            for (int ct = 0; ct < 4; ++ct) acc[rt][ct] = f32x4{0.f, 0.f, 0.f, 0.f};

        #pragma unroll
        for (int ct = 0; ct < 4; ++ct) {
            const int p = ct * 16 + bcol;
            const s16x8 bfr = *reinterpret_cast<const s16x8*>(
                sAb + p * 512 + (((unsigned)(kgrp * 16)) ^ ((unsigned)((p & 7) << 4))));
            #pragma unroll
            for (int rt = 0; rt < 4; ++rt)
                acc[rt][ct] = mfma_bf16(wfr1[rt], bfr, acc[rt][ct]);
        }
        __syncthreads();
        epilogue(b1);
        __syncthreads();
    }

    // ---- layers 2 & 3: K=256, 2-stage weight prefetch pipeline ----
    #pragma unroll 1
    for (int layer = 0; layer < 2; ++layer) {
        const unsigned short* __restrict__ W = wt + 8192 + (layer << 16);
        #pragma unroll
        for (int rt = 0; rt < 4; ++rt)
            #pragma unroll
            for (int ct = 0; ct < 4; ++ct) acc[rt][ct] = f32x4{0.f, 0.f, 0.f, 0.f};

        s16x8 wcur[4];
        #pragma unroll
        for (int rt = 0; rt < 4; ++rt)
            wcur[rt] = *reinterpret_cast<const s16x8*>(
                W + (rowb + rt * 16 + arow) * 256 + kgrp * 8);

        #pragma unroll 1
        for (int ks = 0; ks < 8; ++ks) {
            s16x8 wnxt[4];
            if (ks < 7) {
                #pragma unroll
                for (int rt = 0; rt < 4; ++rt)
                    wnxt[rt] = *reinterpret_cast<const s16x8*>(
                        W + (rowb + rt * 16 + arow) * 256 + (ks + 1) * 32 + kgrp * 8);
            }
            #pragma unroll
            for (int ct = 0; ct < 4; ++ct) {
                const int p = ct * 16 + bcol;
                const s16x8 bfr = *reinterpret_cast<const s16x8*>(
                    sAb + p * 512 + (((unsigned)(ks * 64 + kgrp * 16)) ^ ((unsigned)((p & 7) << 4))));
                #pragma unroll
                for (int rt = 0; rt < 4; ++rt)
                    acc[rt][ct] = mfma_bf16(wcur[rt], bfr, acc[rt][ct]);
            }
            if (ks < 7) {
                #pragma unroll
                for (int rt = 0; rt < 4; ++rt) wcur[rt] = wnxt[rt];
            }
        }
        __syncthreads();
        epilogue(layer == 0 ? b2 : b3);
        __syncthreads();
    }

    // ---- layer 4 via MFMA: A = w4t[16][256] (rows 3-15 zero), B = this wave's 16 points ----
    {
        const unsigned short* __restrict__ W4 = wt + 139264;
        const int p = wid * 16 + bcol;        // this wave's point
        f32x4 a4 = f32x4{0.f, 0.f, 0.f, 0.f};
        #pragma unroll
        for (int ks = 0; ks < 8; ++ks) {
            const s16x8 wfr = *reinterpret_cast<const s16x8*>(W4 + arow * 256 + ks * 32 + kgrp * 8);
            const s16x8 bfr = *reinterpret_cast<const s16x8*>(
                sAb + p * 512 + (((unsigned)(ks * 64 + kgrp * 16)) ^ ((unsigned)((p & 7) << 4))));
            a4 = mfma_bf16(wfr, bfr, a4);
        }
        // D row = kgrp*4 + r, col = bcol -> channels 0-2 live in kgrp==0 lanes, regs 0-2
        if (kgrp == 0) {
            const int pi = p0 + p;
            if (pi < N) {
                #pragma unroll
                for (int c = 0; c < 3; ++c) {
                    const float z = a4[c] + b4[c];
                    out[pi * 3 + c] = 1.0f / (1.0f + expf(-z));
                }
            }
        }
    }
}

// ---- fused fallback (fp32 table, weights in ws) — only if ws can't hold table+feat ----
__global__ __launch_bounds__(NTHREADS, 3)
void fused_hashmlp(const float* __restrict__ x, const float* __restrict__ table,
                   const unsigned short* __restrict__ wt,
                   const float* __restrict__ b1, const float* __restrict__ b2,
                   const float* __restrict__ b3,
                   const float* __restrict__ w4, const float* __restrict__ b4,
                   float* __restrict__ out, int N)
{
    __shared__ float sX[BR][3];
    __shared__ unsigned short sA[BR * 256];
    const int tid = threadIdx.x;
    const int p0  = blockIdx.x * BR;
    if (p0 >= N) return;
    char* sAb = (char*)sA;

    if (tid < BR * 3) sX[tid / 3][tid % 3] = x[p0 * 3 + tid];
    __syncthreads();

    #pragma unroll
    for (int it = 0; it < 4; ++it) {
        const int task = it * NTHREADS + tid;
        const int l = task >> 6;
        const int p = task & 63;
        const float sc  = c_scale[l];
        const float inv = (1.0f / 1.5f);
        const float px = sX[p][0] * inv * sc + 0.5f;
        const float py = sX[p][1] * inv * sc + 0.5f;
        const float pz = sX[p][2] * inv * sc + 0.5f;
        const float fx = floorf(px), fy = floorf(py), fz = floorf(pz);
        const float rx = px - fx, ry = py - fy, rz = pz - fz;
        const unsigned ux = (unsigned)fx, uy = (unsigned)fy, uz = (unsigned)fz;
        const unsigned off = c_off[l];
        const unsigned r1  = c_res1[l];
        const bool dense = (l < 5);
        float ax = 0.0f, ay = 0.0f;
        #pragma unroll
        for (int c = 0; c < 8; ++c) {
            const unsigned bx = c & 1, by = (c >> 1) & 1, bz = (c >> 2) & 1;
            const unsigned cx = ux + bx, cy = uy + by, cz = uz + bz;
            const float wx = bx ? rx : (1.0f - rx);
            const float wy = by ? ry : (1.0f - ry);
            const float wz = bz ? rz : (1.0f - rz);
            const float w = wx * wy * wz;
            unsigned idx;
            if (dense) idx = cx + cy * r1 + cz * r1 * r1;
            else       idx = (cx ^ (cy * 2654435761u) ^ (cz * 805459861u)) & 524287u;
            const float2 tv = *reinterpret_cast<const float2*>(table + 2u * (idx + off));
            ax = fmaf(w, tv.x, ax);
            ay = fmaf(w, tv.y, ay);
        }
        const unsigned pack = (unsigned)f2bf(ax) | ((unsigned)f2bf(ay) << 16);
        *reinterpret_cast<unsigned*>(sAb + p * 512 + ((l * 4) ^ ((p & 7) << 4))) = pack;
    }
    __syncthreads();

    const int lane = tid & 63;
    const int wid  = tid >> 6;
    const int rowb = wid * 64;
    const int arow = lane & 15;
    const int kgrp = lane >> 4;
    const int bcol = lane & 15;

    f32x4 acc[4][4];

    auto epilogue = [&](const float* __restrict__ bias) {
        #pragma unroll
        for (int rt = 0; rt < 4; ++rt) {
            const int f0 = rowb + rt * 16 + kgrp * 4;
            const float4 bv = *reinterpret_cast<const float4*>(bias + f0);
            #pragma unroll
            for (int ct = 0; ct < 4; ++ct) {
                const int p = ct * 16 + bcol;
                const float v0 = fmaxf(acc[rt][ct][0] + bv.x, 0.0f);
                const float v1 = fmaxf(acc[rt][ct][1] + bv.y, 0.0f);
                const float v2 = fmaxf(acc[rt][ct][2] + bv.z, 0.0f);
                const float v3 = fmaxf(acc[rt][ct][3] + bv.w, 0.0f);
                uint2 pk;
                pk.x = (unsigned)f2bf(v0) | ((unsigned)f2bf(v1) << 16);
                pk.y = (unsigned)f2bf(v2) | ((unsigned)f2bf(v3) << 16);
                *reinterpret_cast<uint2*>(
                    sAb + p * 512 + (((unsigned)(2 * f0)) ^ ((unsigned)((p & 7) << 4)))) = pk;
            }
        }
    };

    {
        #pragma unroll
        for (int rt = 0; rt < 4; ++rt)
            #pragma unroll
            for (int ct = 0; ct < 4; ++ct) acc[rt][ct] = f32x4{0.f, 0.f, 0.f, 0.f};
        s16x8 wfr[4];
        #pragma unroll
        for (int rt = 0; rt < 4; ++rt)
            wfr[rt] = *reinterpret_cast<const s16x8*>(wt + (rowb + rt * 16 + arow) * 32 + kgrp * 8);
        #pragma unroll
        for (int ct = 0; ct < 4; ++ct) {
            const int p = ct * 16 + bcol;
            const s16x8 bfr = *reinterpret_cast<const s16x8*>(
                sAb + p * 512 + (((unsigned)(kgrp * 16)) ^ ((unsigned)((p & 7) << 4))));
            #pragma unroll
            for (int rt = 0; rt < 4; ++rt)
                acc[rt][ct] = mfma_bf16(wfr[rt], bfr, acc[rt][ct]);
        }
        __syncthreads();
        epilogue(b1);
        __syncthreads();
    }

    #pragma unroll 1
    for (int layer = 0; layer < 2; ++layer) {
        const unsigned short* __restrict__ W = wt + 8192 + (layer << 16);
        #pragma unroll
        for (int rt = 0; rt < 4; ++rt)
            #pragma unroll
            for (int ct = 0; ct < 4; ++ct) acc[rt][ct] = f32x4{0.f, 0.f, 0.f, 0.f};
        for (int ks = 0; ks < 8; ++ks) {
            s16x8 wfr[4];
            #pragma unroll
            for (int rt = 0; rt < 4; ++rt)
                wfr[rt] = *reinterpret_cast<const s16x8*>(
                    W + (rowb + rt * 16 + arow) * 256 + ks * 32 + kgrp * 8);
            #pragma unroll
            for (int ct = 0; ct < 4; ++ct) {
                const int p = ct * 16 + bcol;
                const s16x8 bfr = *reinterpret_cast<const s16x8*>(
                    sAb + p * 512 + (((unsigned)(ks * 64 + kgrp * 16)) ^ ((unsigned)((p & 7) << 4))));
                #pragma unroll
                for (int rt = 0; rt < 4; ++rt)
                    acc[rt][ct] = mfma_bf16(wfr[rt], bfr, acc[rt][ct]);
            }
        }
        __syncthreads();
        epilogue(layer == 0 ? b2 : b3);
        __syncthreads();
    }

    if (tid < BR * 3) {
        const int r = tid / 3;
        const int c = tid - 3 * r;
        float z0 = 0.0f, z1 = 0.0f;
        for (int kb = 0; kb < 32; kb += 2) {
            const s16x8 hv0 = *reinterpret_cast<const s16x8*>(
                sAb + r * 512 + (((unsigned)(kb * 16)) ^ ((unsigned)((r & 7) << 4))));
            const s16x8 hv1 = *reinterpret_cast<const s16x8*>(
                sAb + r * 512 + (((unsigned)((kb + 1) * 16)) ^ ((unsigned)((r & 7) << 4))));
            #pragma unroll
            for (int j = 0; j < 8; ++j) {
                z0 = fmaf(bf2f((unsigned short)hv0[j]), w4[(kb * 8 + j) * 3 + c], z0);
                z1 = fmaf(bf2f((unsigned short)hv1[j]), w4[((kb + 1) * 8 + j) * 3 + c], z1);
            }
        }
        const float z = z0 + z1 + b4[c];
        const int pi = p0 + r;
        if (pi < N) out[pi * 3 + c] = 1.0f / (1.0f + expf(-z));
    }
}

extern "C" void kernel_launch(void* const* d_in, const int* in_sizes, int n_in,
                              void* d_out, int out_size, void* d_ws, size_t ws_size,
                              hipStream_t stream) {
    const float* x     = (const float*)d_in[0];
    const float* table = (const float*)d_in[1];
    const float* w1    = (const float*)d_in[2];
    const float* b1    = (const float*)d_in[3];
    const float* w2    = (const float*)d_in[4];
    const float* b2    = (const float*)d_in[5];
    const float* w3    = (const float*)d_in[6];
    const float* b3    = (const float*)d_in[7];
    const float* w4    = (const float*)d_in[8];
    const float* b4    = (const float*)d_in[9];
    float* out = (float*)d_out;

    const int N = in_sizes[0] / 3;

    const size_t W_ELEMS    = 143360;                   // bf16 weight elems (incl w4t[16][256])
    const size_t TBL_ELEMS  = 12239728;                 // 2 * TOTAL bf16 table elements
    const size_t need_bf    = (W_ELEMS + TBL_ELEMS) * 2;   // 24.77 MB
    const size_t FEAT_BYTES = (size_t)N * 64;              // uint2[8][N]
    const size_t need_split = need_bf + FEAT_BYTES;        // ~58.3 MB

    unsigned short* wsw = (unsigned short*)d_ws;
    unsigned short* tbf = wsw + W_ELEMS;
    uint2* feat2 = (uint2*)((char*)d_ws + need_bf);     // 8B-aligned

    hipLaunchKernelGGL(convert_w, dim3(560), dim3(256), 0, stream, w1, w2, w3, w4, wsw);

    if (ws_size >= need_split) {
        const size_t n4 = TBL_ELEMS / 4;
        hipLaunchKernelGGL(convert_table, dim3((unsigned)((n4 + 255) / 256)), dim3(256), 0, stream,
                           table, tbf, (int)n4);
        hipLaunchKernelGGL(encode_kernel, dim3((N + 255) / 256, 8), dim3(256), 0, stream,
                           x, tbf, feat2, N);
        hipLaunchKernelGGL(mlp_kernel, dim3((N + BR - 1) / BR), dim3(NTHREADS), 0, stream,
                           feat2, wsw, b1, b2, b3, b4, out, N);
    } else {
        hipLaunchKernelGGL(fused_hashmlp, dim3((N + BR - 1) / BR), dim3(NTHREADS), 0, stream,
                           x, table, wsw, b1, b2, b3, w4, b4, out, N);
    }
}

// Round 10
// 564.400 us; speedup vs baseline: 1.6100x; 1.0828x over previous
//
#include <hip/hip_runtime.h>
#include <hip/hip_bf16.h>
#include <math.h>

#define NTHREADS 256
#define BR 64

typedef __attribute__((ext_vector_type(8))) short   s16x8;
typedef __attribute__((ext_vector_type(8))) __bf16  bf16x8;
typedef __attribute__((ext_vector_type(4))) float   f32x4;
typedef __attribute__((ext_vector_type(2))) float   f32x2;

// ---- Compile-time hash-grid constants (verified exact: absmax 0.0 rounds 1,3,4,6-9) ----
__device__ __constant__ float c_scale[16] = {
    15.0f,        21.110607f,  29.554930f,  41.224254f,
    57.350239f,   79.634946f,  110.430473f, 152.987205f,
    211.796890f,  293.066769f, 405.374657f, 560.574388f,
    775.046906f,  1071.429232f, 1481.003616f, 2047.0f
};
__device__ __constant__ unsigned c_off[16] = {
    0u,        4920u,     18744u,    51512u,
    136696u,   352696u,   876984u,   1401272u,
    1925560u,  2449848u,  2974136u,  3498424u,
    4022712u,  4547000u,  5071288u,  5595576u
};
__device__ __constant__ unsigned c_res1[16] = {
    17u, 24u, 32u, 44u, 60u, 0u,0u,0u,0u,0u,0u,0u,0u,0u,0u,0u
};

#define TBL_SCALE     8192.0f          // table stored as fp8 e4m3 of v*2^13 (raw +-1e-4 is
#define TBL_SCALE_INV (1.0f/8192.0f)   // below e4m3 subnormal floor 2^-9; scaled is normal)

__device__ inline unsigned short f2bf(float f) {
    unsigned u = __builtin_bit_cast(unsigned, f);
    u += 0x7FFFu + ((u >> 16) & 1u);          // round-to-nearest-even
    return (unsigned short)(u >> 16);
}
__device__ inline float bf2f(unsigned short h) {
    unsigned u = ((unsigned)h) << 16;
    return __builtin_bit_cast(float, u);
}
// HW packed f32->bf16 RNE convert (verified r8/r9: absmax 0.0)
__device__ inline unsigned cvtpk(float lo, float hi) {
    unsigned r;
    asm("v_cvt_pk_bf16_f32 %0, %1, %2" : "=v"(r) : "v"(lo), "v"(hi));
    return r;
}
__device__ inline f32x4 mfma_bf16(s16x8 a, s16x8 b, f32x4 c) {
    return __builtin_amdgcn_mfma_f32_16x16x32_bf16(
        __builtin_bit_cast(bf16x8, a), __builtin_bit_cast(bf16x8, b), c, 0, 0, 0);
}

// ws layout (bytes): wt bf16[143360] @0 (wt1/wt2/wt3/w4t as before) ;
// fp8 table ushort[TOTAL] @286720 ; feat2 uint2[8][N] @12526448 (8B-aligned).
__global__ void convert_w(const float* __restrict__ w1, const float* __restrict__ w2,
                          const float* __restrict__ w3, const float* __restrict__ w4,
                          unsigned short* __restrict__ ws) {
    int t = blockIdx.x * blockDim.x + threadIdx.x;
    if (t < 8192) {
        int col = t >> 5, k = t & 31;
        ws[t] = f2bf(w1[k * 256 + col]);
    } else if (t < 73728) {
        int u = t - 8192; int col = u >> 8, k = u & 255;
        ws[t] = f2bf(w2[k * 256 + col]);
    } else if (t < 139264) {
        int u = t - 73728; int col = u >> 8, k = u & 255;
        ws[t] = f2bf(w3[k * 256 + col]);
    } else if (t < 143360) {
        int u = t - 139264; int ch = u >> 8, k = u & 255;
        ws[t] = (ch < 3) ? f2bf(w4[k * 3 + ch]) : (unsigned short)0;
    }
}

// table entry (float2) -> 2 x fp8 e4m3 of v*8192, packed in one ushort
__global__ void convert_table_fp8(const float* __restrict__ t, unsigned short* __restrict__ o, int n) {
    int i = blockIdx.x * blockDim.x + threadIdx.x;
    if (i < n) {
        const float2 v = ((const float2*)t)[i];
        const int pk = __builtin_amdgcn_cvt_pk_fp8_f32(v.x * TBL_SCALE, v.y * TBL_SCALE, 0, false);
        o[i] = (unsigned short)(pk & 0xFFFF);
    }
}

// ---- encode: 2D grid, lp = blockIdx.y; x-major dispatch => whole chip does ONE
// level-pair at a time. fp8 table: hashed level-pair working set 4MB -> 1MB,
// fits each XCD's private 4MB L2 with room (r10 change). ----
__global__ __launch_bounds__(256)
void encode_kernel(const float* __restrict__ x, const unsigned short* __restrict__ tbf8,
                   uint2* __restrict__ feat2, int N)
{
    const int p  = blockIdx.x * 256 + threadIdx.x;
    const int lp = blockIdx.y;                 // 0..7, wave-uniform
    if (p >= N) return;

    const float inv = (1.0f / 1.5f);
    const float xc = x[3 * p + 0] * inv;
    const float yc = x[3 * p + 1] * inv;
    const float zc = x[3 * p + 2] * inv;

    unsigned outv[2];
    #pragma unroll
    for (int s = 0; s < 2; ++s) {
        const int l = lp * 2 + s;              // uniform
        const float sc = c_scale[l];
        const float px = xc * sc + 0.5f;
        const float py = yc * sc + 0.5f;
        const float pz = zc * sc + 0.5f;
        const float fx = floorf(px), fy = floorf(py), fz = floorf(pz);
        const float rx = px - fx, ry = py - fy, rz = pz - fz;
        const unsigned ux = (unsigned)fx, uy = (unsigned)fy, uz = (unsigned)fz;
        const unsigned off = c_off[l];
        const unsigned r1  = c_res1[l];
        const bool dense = (l < 5);            // uniform
        float ax = 0.0f, ay = 0.0f;
        #pragma unroll
        for (int c = 0; c < 8; ++c) {
            const unsigned bx = c & 1, by = (c >> 1) & 1, bz = (c >> 2) & 1;
            const unsigned cx = ux + bx, cy = uy + by, cz = uz + bz;
            const float wx = bx ? rx : (1.0f - rx);
            const float wy = by ? ry : (1.0f - ry);
            const float wz = bz ? rz : (1.0f - rz);
            const float w = wx * wy * wz;
            unsigned idx;
            if (dense) idx = cx + cy * r1 + cz * r1 * r1;
            else       idx = (cx ^ (cy * 2654435761u) ^ (cz * 805459861u)) & 524287u;
            const unsigned short v = tbf8[idx + off];
            const f32x2 tv = __builtin_amdgcn_cvt_pk_f32_fp8((int)v, false);
            ax = fmaf(w, tv[0], ax);
            ay = fmaf(w, tv[1], ay);
        }
        outv[s] = cvtpk(ax * TBL_SCALE_INV, ay * TBL_SCALE_INV);
    }
    feat2[(size_t)lp * N + p] = make_uint2(outv[0], outv[1]);   // 512B/wave coalesced
}

// ---- MLP: r8 structure verbatim (NO weight prefetch: r9 showed +4 VGPR crosses the
// 128-reg unified-file cliff -> 4->3 waves/SIMD, cancels the gain). VGPR 64 + 64 AGPR
// = 128 exactly -> 4 waves/SIMD at __launch_bounds__(256,3). ----
__global__ __launch_bounds__(NTHREADS, 3)
void mlp_kernel(const uint2* __restrict__ feat2,
                const unsigned short* __restrict__ wt,
                const float* __restrict__ b1, const float* __restrict__ b2,
                const float* __restrict__ b3, const float* __restrict__ b4,
                float* __restrict__ out, int N)
{
    __shared__ unsigned short sA[BR * 256];   // 32 KB, rows of 512B, XOR-swizzled
    char* sAb = (char*)sA;

    const int tid = threadIdx.x;
    const int p0  = blockIdx.x * BR;
    if (p0 >= N) return;

    // ---- A-tile load: 512 uint2 (8 planes x 64 points), coalesced reads ----
    #pragma unroll
    for (int it = 0; it < 2; ++it) {
        const int t  = it * NTHREADS + tid;
        const int lp = t >> 6;                 // plane 0..7
        const int p  = t & 63;
        const uint2 v = feat2[(size_t)lp * N + p0 + p];
        *reinterpret_cast<uint2*>(
            sAb + p * 512 + (((unsigned)(lp * 8)) ^ ((unsigned)((p & 7) << 4)))) = v;
    }
    __syncthreads();

    const int lane = tid & 63;
    const int wid  = tid >> 6;
    const int rowb = wid * 64;           // wave's 64-FEATURE slice (output rows)
    const int arow = lane & 15;          // A-frag row  = output feature (within 16)
    const int kgrp = lane >> 4;          // k-offset group (k0 = kgrp*8)
    const int bcol = lane & 15;          // B-frag col   = point (within 16)

    f32x4 acc[4][4];                     // [feature-tile rt][point-tile ct]

    auto epilogue = [&](const float* __restrict__ bias) {
        #pragma unroll
        for (int rt = 0; rt < 4; ++rt) {
            const int f0 = rowb + rt * 16 + kgrp * 4;       // 4 consecutive features
            const float4 bv = *reinterpret_cast<const float4*>(bias + f0);
            #pragma unroll
            for (int ct = 0; ct < 4; ++ct) {
                const int p = ct * 16 + bcol;
                const float v0 = fmaxf(acc[rt][ct][0] + bv.x, 0.0f);
                const float v1 = fmaxf(acc[rt][ct][1] + bv.y, 0.0f);
                const float v2 = fmaxf(acc[rt][ct][2] + bv.z, 0.0f);
                const float v3 = fmaxf(acc[rt][ct][3] + bv.w, 0.0f);
                uint2 pk;
                pk.x = cvtpk(v0, v1);
                pk.y = cvtpk(v2, v3);
                *reinterpret_cast<uint2*>(
                    sAb + p * 512 + (((unsigned)(2 * f0)) ^ ((unsigned)((p & 7) << 4)))) = pk;
            }
        }
    };

    // ---- layer 1: K=32, single MFMA per (rt,ct) ----
    {
        #pragma unroll
        for (int rt = 0; rt < 4; ++rt)
            #pragma unroll
            for (int ct = 0; ct < 4; ++ct) acc[rt][ct] = f32x4{0.f, 0.f, 0.f, 0.f};

        s16x8 wfr[4];
        #pragma unroll
        for (int rt = 0; rt < 4; ++rt)
            wfr[rt] = *reinterpret_cast<const s16x8*>(wt + (rowb + rt * 16 + arow) * 32 + kgrp * 8);
        #pragma unroll
        for (int ct = 0; ct < 4; ++ct) {
            const int p = ct * 16 + bcol;
            const s16x8 bfr = *reinterpret_cast<const s16x8*>(
                sAb + p * 512 + (((unsigned)(kgrp * 16)) ^ ((unsigned)((p & 7) << 4))));
            #pragma unroll
            for (int rt = 0; rt < 4; ++rt)
                acc[rt][ct] = mfma_bf16(wfr[rt], bfr, acc[rt][ct]);
        }
        __syncthreads();
        epilogue(b1);
        __syncthreads();
    }

    // ---- layers 2 & 3: K=256 ----
    #pragma unroll 1
    for (int layer = 0; layer < 2; ++layer) {
        const unsigned short* __restrict__ W = wt + 8192 + (layer << 16);
        #pragma unroll
        for (int rt = 0; rt < 4; ++rt)
            #pragma unroll
            for (int ct = 0; ct < 4; ++ct) acc[rt][ct] = f32x4{0.f, 0.f, 0.f, 0.f};

        for (int ks = 0; ks < 8; ++ks) {
            s16x8 wfr[4];
            #pragma unroll
            for (int rt = 0; rt < 4; ++rt)
                wfr[rt] = *reinterpret_cast<const s16x8*>(
                    W + (rowb + rt * 16 + arow) * 256 + ks * 32 + kgrp * 8);
            #pragma unroll
            for (int ct = 0; ct < 4; ++ct) {
                const int p = ct * 16 + bcol;
                const s16x8 bfr = *reinterpret_cast<const s16x8*>(
                    sAb + p * 512 + (((unsigned)(ks * 64 + kgrp * 16)) ^ ((unsigned)((p & 7) << 4))));
                #pragma unroll
                for (int rt = 0; rt < 4; ++rt)
                    acc[rt][ct] = mfma_bf16(wfr[rt], bfr, acc[rt][ct]);
            }
        }
        __syncthreads();
        epilogue(layer == 0 ? b2 : b3);
        __syncthreads();
    }

    // ---- layer 4 via MFMA: A = w4t[16][256] (rows 3-15 zero), B = this wave's 16 points ----
    {
        const unsigned short* __restrict__ W4 = wt + 139264;
        const int p = wid * 16 + bcol;        // this wave's point
        f32x4 a4 = f32x4{0.f, 0.f, 0.f, 0.f};
        #pragma unroll
        for (int ks = 0; ks < 8; ++ks) {
            const s16x8 wfr = *reinterpret_cast<const s16x8*>(W4 + arow * 256 + ks * 32 + kgrp * 8);
            const s16x8 bfr = *reinterpret_cast<const s16x8*>(
                sAb + p * 512 + (((unsigned)(ks * 64 + kgrp * 16)) ^ ((unsigned)((p & 7) << 4))));
            a4 = mfma_bf16(wfr, bfr, a4);
        }
        // D row = kgrp*4 + r, col = bcol -> channels 0-2 live in kgrp==0 lanes, regs 0-2
        if (kgrp == 0) {
            const int pi = p0 + p;
            if (pi < N) {
                #pragma unroll
                for (int c = 0; c < 3; ++c) {
                    const float z = a4[c] + b4[c];
                    out[pi * 3 + c] = 1.0f / (1.0f + expf(-z));
                }
            }
        }
    }
}

// ---- fused fallback (fp32 table, weights in ws) — only if ws can't hold table+feat ----
__global__ __launch_bounds__(NTHREADS, 3)
void fused_hashmlp(const float* __restrict__ x, const float* __restrict__ table,
                   const unsigned short* __restrict__ wt,
                   const float* __restrict__ b1, const float* __restrict__ b2,
                   const float* __restrict__ b3,
                   const float* __restrict__ w4, const float* __restrict__ b4,
                   float* __restrict__ out, int N)
{
    __shared__ float sX[BR][3];
    __shared__ unsigned short sA[BR * 256];
    const int tid = threadIdx.x;
    const int p0  = blockIdx.x * BR;
    if (p0 >= N) return;
    char* sAb = (char*)sA;

    if (tid < BR * 3) sX[tid / 3][tid % 3] = x[p0 * 3 + tid];
    __syncthreads();

    #pragma unroll
    for (int it = 0; it < 4; ++it) {
        const int task = it * NTHREADS + tid;
        const int l = task >> 6;
        const int p = task & 63;
        const float sc  = c_scale[l];
        const float inv = (1.0f / 1.5f);
        const float px = sX[p][0] * inv * sc + 0.5f;
        const float py = sX[p][1] * inv * sc + 0.5f;
        const float pz = sX[p][2] * inv * sc + 0.5f;
        const float fx = floorf(px), fy = floorf(py), fz = floorf(pz);
        const float rx = px - fx, ry = py - fy, rz = pz - fz;
        const unsigned ux = (unsigned)fx, uy = (unsigned)fy, uz = (unsigned)fz;
        const unsigned off = c_off[l];
        const unsigned r1  = c_res1[l];
        const bool dense = (l < 5);
        float ax = 0.0f, ay = 0.0f;
        #pragma unroll
        for (int c = 0; c < 8; ++c) {
            const unsigned bx = c & 1, by = (c >> 1) & 1, bz = (c >> 2) & 1;
            const unsigned cx = ux + bx, cy = uy + by, cz = uz + bz;
            const float wx = bx ? rx : (1.0f - rx);
            const float wy = by ? ry : (1.0f - ry);
            const float wz = bz ? rz : (1.0f - rz);
            const float w = wx * wy * wz;
            unsigned idx;
            if (dense) idx = cx + cy * r1 + cz * r1 * r1;
            else       idx = (cx ^ (cy * 2654435761u) ^ (cz * 805459861u)) & 524287u;
            const float2 tv = *reinterpret_cast<const float2*>(table + 2u * (idx + off));
            ax = fmaf(w, tv.x, ax);
            ay = fmaf(w, tv.y, ay);
        }
        const unsigned pack = (unsigned)f2bf(ax) | ((unsigned)f2bf(ay) << 16);
        *reinterpret_cast<unsigned*>(sAb + p * 512 + ((l * 4) ^ ((p & 7) << 4))) = pack;
    }
    __syncthreads();

    const int lane = tid & 63;
    const int wid  = tid >> 6;
    const int rowb = wid * 64;
    const int arow = lane & 15;
    const int kgrp = lane >> 4;
    const int bcol = lane & 15;

    f32x4 acc[4][4];

    auto epilogue = [&](const float* __restrict__ bias) {
        #pragma unroll
        for (int rt = 0; rt < 4; ++rt) {
            const int f0 = rowb + rt * 16 + kgrp * 4;
            const float4 bv = *reinterpret_cast<const float4*>(bias + f0);
            #pragma unroll
            for (int ct = 0; ct < 4; ++ct) {
                const int p = ct * 16 + bcol;
                const float v0 = fmaxf(acc[rt][ct][0] + bv.x, 0.0f);
                const float v1 = fmaxf(acc[rt][ct][1] + bv.y, 0.0f);
                const float v2 = fmaxf(acc[rt][ct][2] + bv.z, 0.0f);
                const float v3 = fmaxf(acc[rt][ct][3] + bv.w, 0.0f);
                uint2 pk;
                pk.x = (unsigned)f2bf(v0) | ((unsigned)f2bf(v1) << 16);
                pk.y = (unsigned)f2bf(v2) | ((unsigned)f2bf(v3) << 16);
                *reinterpret_cast<uint2*>(
                    sAb + p * 512 + (((unsigned)(2 * f0)) ^ ((unsigned)((p & 7) << 4)))) = pk;
            }
        }
    };

    {
        #pragma unroll
        for (int rt = 0; rt < 4; ++rt)
            #pragma unroll
            for (int ct = 0; ct < 4; ++ct) acc[rt][ct] = f32x4{0.f, 0.f, 0.f, 0.f};
        s16x8 wfr[4];
        #pragma unroll
        for (int rt = 0; rt < 4; ++rt)
            wfr[rt] = *reinterpret_cast<const s16x8*>(wt + (rowb + rt * 16 + arow) * 32 + kgrp * 8);
        #pragma unroll
        for (int ct = 0; ct < 4; ++ct) {
            const int p = ct * 16 + bcol;
            const s16x8 bfr = *reinterpret_cast<const s16x8*>(
                sAb + p * 512 + (((unsigned)(kgrp * 16)) ^ ((unsigned)((p & 7) << 4))));
            #pragma unroll
            for (int rt = 0; rt < 4; ++rt)
                acc[rt][ct] = mfma_bf16(wfr[rt], bfr, acc[rt][ct]);
        }
        __syncthreads();
        epilogue(b1);
        __syncthreads();
    }

    #pragma unroll 1
    for (int layer = 0; layer < 2; ++layer) {
        const unsigned short* __restrict__ W = wt + 8192 + (layer << 16);
        #pragma unroll
        for (int rt = 0; rt < 4; ++rt)
            #pragma unroll
            for (int ct = 0; ct < 4; ++ct) acc[rt][ct] = f32x4{0.f, 0.f, 0.f, 0.f};
        for (int ks = 0; ks < 8; ++ks) {
            s16x8 wfr[4];
            #pragma unroll
            for (int rt = 0; rt < 4; ++rt)
                wfr[rt] = *reinterpret_cast<const s16x8*>(
                    W + (rowb + rt * 16 + arow) * 256 + ks * 32 + kgrp * 8);
            #pragma unroll
            for (int ct = 0; ct < 4; ++ct) {
                const int p = ct * 16 + bcol;
                const s16x8 bfr = *reinterpret_cast<const s16x8*>(
                    sAb + p * 512 + (((unsigned)(ks * 64 + kgrp * 16)) ^ ((unsigned)((p & 7) << 4))));
                #pragma unroll
                for (int rt = 0; rt < 4; ++rt)
                    acc[rt][ct] = mfma_bf16(wfr[rt], bfr, acc[rt][ct]);
            }
        }
        __syncthreads();
        epilogue(layer == 0 ? b2 : b3);
        __syncthreads();
    }

    if (tid < BR * 3) {
        const int r = tid / 3;
        const int c = tid - 3 * r;
        float z0 = 0.0f, z1 = 0.0f;
        for (int kb = 0; kb < 32; kb += 2) {
            const s16x8 hv0 = *reinterpret_cast<const s16x8*>(
                sAb + r * 512 + (((unsigned)(kb * 16)) ^ ((unsigned)((r & 7) << 4))));
            const s16x8 hv1 = *reinterpret_cast<const s16x8*>(
                sAb + r * 512 + (((unsigned)((kb + 1) * 16)) ^ ((unsigned)((r & 7) << 4))));
            #pragma unroll
            for (int j = 0; j < 8; ++j) {
                z0 = fmaf(bf2f((unsigned short)hv0[j]), w4[(kb * 8 + j) * 3 + c], z0);
                z1 = fmaf(bf2f((unsigned short)hv1[j]), w4[((kb + 1) * 8 + j) * 3 + c], z1);
            }
        }
        const float z = z0 + z1 + b4[c];
        const int pi = p0 + r;
        if (pi < N) out[pi * 3 + c] = 1.0f / (1.0f + expf(-z));
    }
}

extern "C" void kernel_launch(void* const* d_in, const int* in_sizes, int n_in,
                              void* d_out, int out_size, void* d_ws, size_t ws_size,
                              hipStream_t stream) {
    const float* x     = (const float*)d_in[0];
    const float* table = (const float*)d_in[1];
    const float* w1    = (const float*)d_in[2];
    const float* b1    = (const float*)d_in[3];
    const float* w2    = (const float*)d_in[4];
    const float* b2    = (const float*)d_in[5];
    const float* w3    = (const float*)d_in[6];
    const float* b3    = (const float*)d_in[7];
    const float* w4    = (const float*)d_in[8];
    const float* b4    = (const float*)d_in[9];
    float* out = (float*)d_out;

    const int N = in_sizes[0] / 3;

    const size_t W_ELEMS    = 143360;                     // bf16 weight elems (incl w4t)
    const size_t TOTAL_E    = 6119864;                    // table entries
    const size_t wt_bytes   = W_ELEMS * 2;                // 286720
    const size_t tbl_bytes  = TOTAL_E * 2;                // fp8 pairs: 2B/entry = 12239728
    const size_t need_bf    = wt_bytes + tbl_bytes;       // 12526448 (8B-aligned)
    const size_t FEAT_BYTES = (size_t)N * 64;             // uint2[8][N]
    const size_t need_split = need_bf + FEAT_BYTES;       // ~46 MB

    unsigned short* wsw  = (unsigned short*)d_ws;
    unsigned short* tbf8 = (unsigned short*)((char*)d_ws + wt_bytes);
    uint2* feat2 = (uint2*)((char*)d_ws + need_bf);

    hipLaunchKernelGGL(convert_w, dim3(560), dim3(256), 0, stream, w1, w2, w3, w4, wsw);

    if (ws_size >= need_split) {
        hipLaunchKernelGGL(convert_table_fp8, dim3((unsigned)((TOTAL_E + 255) / 256)), dim3(256),
                           0, stream, table, tbf8, (int)TOTAL_E);
        hipLaunchKernelGGL(encode_kernel, dim3((N + 255) / 256, 8), dim3(256), 0, stream,
                           x, tbf8, feat2, N);
        hipLaunchKernelGGL(mlp_kernel, dim3((N + BR - 1) / BR), dim3(NTHREADS), 0, stream,
                           feat2, wsw, b1, b2, b3, b4, out, N);
    } else {
        hipLaunchKernelGGL(fused_hashmlp, dim3((N + BR - 1) / BR), dim3(NTHREADS), 0, stream,
                           x, table, wsw, b1, b2, b3, w4, b4, out, N);
    }
}

// Round 11
// 558.941 us; speedup vs baseline: 1.6257x; 1.0098x over previous
//
#include <hip/hip_runtime.h>
#include <hip/hip_bf16.h>
#include <math.h>

#define NTHREADS 256
#define BR 64

typedef __attribute__((ext_vector_type(8))) short   s16x8;
typedef __attribute__((ext_vector_type(8))) __bf16  bf16x8;
typedef __attribute__((ext_vector_type(4))) float   f32x4;
typedef __attribute__((ext_vector_type(2))) float   f32x2;

// ---- Compile-time hash-grid constants (verified exact: absmax 0.0 rounds 1,3,4,6-10) ----
__device__ __constant__ float c_scale[16] = {
    15.0f,        21.110607f,  29.554930f,  41.224254f,
    57.350239f,   79.634946f,  110.430473f, 152.987205f,
    211.796890f,  293.066769f, 405.374657f, 560.574388f,
    775.046906f,  1071.429232f, 1481.003616f, 2047.0f
};
__device__ __constant__ unsigned c_off[16] = {
    0u,        4920u,     18744u,    51512u,
    136696u,   352696u,   876984u,   1401272u,
    1925560u,  2449848u,  2974136u,  3498424u,
    4022712u,  4547000u,  5071288u,  5595576u
};
__device__ __constant__ unsigned c_res1[16] = {
    17u, 24u, 32u, 44u, 60u, 0u,0u,0u,0u,0u,0u,0u,0u,0u,0u,0u
};

#define TBL_SCALE     8192.0f          // table stored as fp8 e4m3 of v*2^13 (raw +-1e-4 is
#define TBL_SCALE_INV (1.0f/8192.0f)   // below e4m3 subnormal floor 2^-9; scaled is normal)

__device__ inline unsigned short f2bf(float f) {
    unsigned u = __builtin_bit_cast(unsigned, f);
    u += 0x7FFFu + ((u >> 16) & 1u);          // round-to-nearest-even
    return (unsigned short)(u >> 16);
}
__device__ inline float bf2f(unsigned short h) {
    unsigned u = ((unsigned)h) << 16;
    return __builtin_bit_cast(float, u);
}
// HW packed f32->bf16 RNE convert (verified r8-r10: absmax 0.0)
__device__ inline unsigned cvtpk(float lo, float hi) {
    unsigned r;
    asm("v_cvt_pk_bf16_f32 %0, %1, %2" : "=v"(r) : "v"(lo), "v"(hi));
    return r;
}
__device__ inline f32x4 mfma_bf16(s16x8 a, s16x8 b, f32x4 c) {
    return __builtin_amdgcn_mfma_f32_16x16x32_bf16(
        __builtin_bit_cast(bf16x8, a), __builtin_bit_cast(bf16x8, b), c, 0, 0, 0);
}

// ws layout (bytes): wt bf16[143360] @0 (wt1/wt2/wt3/w4t) ;
// fp8 table ushort[TOTAL] @286720 ; feat2 uint2[8][N] @12526448 (8B-aligned).
__global__ void convert_w(const float* __restrict__ w1, const float* __restrict__ w2,
                          const float* __restrict__ w3, const float* __restrict__ w4,
                          unsigned short* __restrict__ ws) {
    int t = blockIdx.x * blockDim.x + threadIdx.x;
    if (t < 8192) {
        int col = t >> 5, k = t & 31;
        ws[t] = f2bf(w1[k * 256 + col]);
    } else if (t < 73728) {
        int u = t - 8192; int col = u >> 8, k = u & 255;
        ws[t] = f2bf(w2[k * 256 + col]);
    } else if (t < 139264) {
        int u = t - 73728; int col = u >> 8, k = u & 255;
        ws[t] = f2bf(w3[k * 256 + col]);
    } else if (t < 143360) {
        int u = t - 139264; int ch = u >> 8, k = u & 255;
        ws[t] = (ch < 3) ? f2bf(w4[k * 3 + ch]) : (unsigned short)0;
    }
}

// table entry (float2) -> 2 x fp8 e4m3 of v*8192, packed in one ushort
__global__ void convert_table_fp8(const float* __restrict__ t, unsigned short* __restrict__ o, int n) {
    int i = blockIdx.x * blockDim.x + threadIdx.x;
    if (i < n) {
        const float2 v = ((const float2*)t)[i];
        const int pk = __builtin_amdgcn_cvt_pk_fp8_f32(v.x * TBL_SCALE, v.y * TBL_SCALE, 0, false);
        o[i] = (unsigned short)(pk & 0xFFFF);
    }
}

// ---- encode: 2D grid, lp = blockIdx.y; whole chip does ONE level-pair at a time
// (fp8: 1MB/hashed-pair, L2-resident). r11: batch ALL 16 corner loads (both levels)
// before consuming — per-thread outstanding gathers 8 -> 16 to cover ~200cyc L2
// latency (encode was MLP-bound at ~237us vs ~110us TA floor). ----
__global__ __launch_bounds__(256)
void encode_kernel(const float* __restrict__ x, const unsigned short* __restrict__ tbf8,
                   uint2* __restrict__ feat2, int N)
{
    const int p  = blockIdx.x * 256 + threadIdx.x;
    const int lp = blockIdx.y;                 // 0..7, wave-uniform
    if (p >= N) return;

    const float inv = (1.0f / 1.5f);
    const float xc = x[3 * p + 0] * inv;
    const float yc = x[3 * p + 1] * inv;
    const float zc = x[3 * p + 2] * inv;

    // ---- phase 1: compute all 16 global indices (2 levels x 8 corners) ----
    unsigned idxa[2][8];
    float rxa[2], rya[2], rza[2];
    #pragma unroll
    for (int s = 0; s < 2; ++s) {
        const int l = lp * 2 + s;              // uniform
        const float sc = c_scale[l];
        const float px = xc * sc + 0.5f;
        const float py = yc * sc + 0.5f;
        const float pz = zc * sc + 0.5f;
        const float fx = floorf(px), fy = floorf(py), fz = floorf(pz);
        rxa[s] = px - fx; rya[s] = py - fy; rza[s] = pz - fz;
        const unsigned ux = (unsigned)fx, uy = (unsigned)fy, uz = (unsigned)fz;
        const unsigned off = c_off[l];
        const unsigned r1  = c_res1[l];
        const bool dense = (l < 5);            // uniform
        #pragma unroll
        for (int c = 0; c < 8; ++c) {
            const unsigned cx = ux + (c & 1), cy = uy + ((c >> 1) & 1), cz = uz + ((c >> 2) & 1);
            unsigned idx;
            if (dense) idx = cx + cy * r1 + cz * r1 * r1;
            else       idx = (cx ^ (cy * 2654435761u) ^ (cz * 805459861u)) & 524287u;
            idxa[s][c] = idx + off;
        }
    }

    // ---- phase 2: issue all 16 loads back-to-back (16 outstanding) ----
    unsigned short va[2][8];
    #pragma unroll
    for (int s = 0; s < 2; ++s)
        #pragma unroll
        for (int c = 0; c < 8; ++c)
            va[s][c] = tbf8[idxa[s][c]];

    // ---- phase 3: consume (weights recomputed from cached fracs) ----
    unsigned outv[2];
    #pragma unroll
    for (int s = 0; s < 2; ++s) {
        float ax = 0.0f, ay = 0.0f;
        #pragma unroll
        for (int c = 0; c < 8; ++c) {
            const float wx = (c & 1) ? rxa[s] : (1.0f - rxa[s]);
            const float wy = ((c >> 1) & 1) ? rya[s] : (1.0f - rya[s]);
            const float wz = ((c >> 2) & 1) ? rza[s] : (1.0f - rza[s]);
            const float w = wx * wy * wz;
            const f32x2 tv = __builtin_amdgcn_cvt_pk_f32_fp8((int)va[s][c], false);
            ax = fmaf(w, tv[0], ax);
            ay = fmaf(w, tv[1], ay);
        }
        outv[s] = cvtpk(ax * TBL_SCALE_INV, ay * TBL_SCALE_INV);
    }
    feat2[(size_t)lp * N + p] = make_uint2(outv[0], outv[1]);   // 512B/wave coalesced
}

// ---- MLP: r8 structure verbatim (r9 lesson: +4 VGPR crosses the 128-reg cliff).
// VGPR 64 + 64 AGPR = 128 exactly -> 4 waves/SIMD at __launch_bounds__(256,3). ----
__global__ __launch_bounds__(NTHREADS, 3)
void mlp_kernel(const uint2* __restrict__ feat2,
                const unsigned short* __restrict__ wt,
                const float* __restrict__ b1, const float* __restrict__ b2,
                const float* __restrict__ b3, const float* __restrict__ b4,
                float* __restrict__ out, int N)
{
    __shared__ unsigned short sA[BR * 256];   // 32 KB, rows of 512B, XOR-swizzled
    char* sAb = (char*)sA;

    const int tid = threadIdx.x;
    const int p0  = blockIdx.x * BR;
    if (p0 >= N) return;

    // ---- A-tile load: 512 uint2 (8 planes x 64 points), coalesced reads ----
    #pragma unroll
    for (int it = 0; it < 2; ++it) {
        const int t  = it * NTHREADS + tid;
        const int lp = t >> 6;                 // plane 0..7
        const int p  = t & 63;
        const uint2 v = feat2[(size_t)lp * N + p0 + p];
        *reinterpret_cast<uint2*>(
            sAb + p * 512 + (((unsigned)(lp * 8)) ^ ((unsigned)((p & 7) << 4)))) = v;
    }
    __syncthreads();

    const int lane = tid & 63;
    const int wid  = tid >> 6;
    const int rowb = wid * 64;           // wave's 64-FEATURE slice (output rows)
    const int arow = lane & 15;          // A-frag row  = output feature (within 16)
    const int kgrp = lane >> 4;          // k-offset group (k0 = kgrp*8)
    const int bcol = lane & 15;          // B-frag col   = point (within 16)

    f32x4 acc[4][4];                     // [feature-tile rt][point-tile ct]

    auto epilogue = [&](const float* __restrict__ bias) {
        #pragma unroll
        for (int rt = 0; rt < 4; ++rt) {
            const int f0 = rowb + rt * 16 + kgrp * 4;       // 4 consecutive features
            const float4 bv = *reinterpret_cast<const float4*>(bias + f0);
            #pragma unroll
            for (int ct = 0; ct < 4; ++ct) {
                const int p = ct * 16 + bcol;
                const float v0 = fmaxf(acc[rt][ct][0] + bv.x, 0.0f);
                const float v1 = fmaxf(acc[rt][ct][1] + bv.y, 0.0f);
                const float v2 = fmaxf(acc[rt][ct][2] + bv.z, 0.0f);
                const float v3 = fmaxf(acc[rt][ct][3] + bv.w, 0.0f);
                uint2 pk;
                pk.x = cvtpk(v0, v1);
                pk.y = cvtpk(v2, v3);
                *reinterpret_cast<uint2*>(
                    sAb + p * 512 + (((unsigned)(2 * f0)) ^ ((unsigned)((p & 7) << 4)))) = pk;
            }
        }
    };

    // ---- layer 1: K=32, single MFMA per (rt,ct) ----
    {
        #pragma unroll
        for (int rt = 0; rt < 4; ++rt)
            #pragma unroll
            for (int ct = 0; ct < 4; ++ct) acc[rt][ct] = f32x4{0.f, 0.f, 0.f, 0.f};

        s16x8 wfr[4];
        #pragma unroll
        for (int rt = 0; rt < 4; ++rt)
            wfr[rt] = *reinterpret_cast<const s16x8*>(wt + (rowb + rt * 16 + arow) * 32 + kgrp * 8);
        #pragma unroll
        for (int ct = 0; ct < 4; ++ct) {
            const int p = ct * 16 + bcol;
            const s16x8 bfr = *reinterpret_cast<const s16x8*>(
                sAb + p * 512 + (((unsigned)(kgrp * 16)) ^ ((unsigned)((p & 7) << 4))));
            #pragma unroll
            for (int rt = 0; rt < 4; ++rt)
                acc[rt][ct] = mfma_bf16(wfr[rt], bfr, acc[rt][ct]);
        }
        __syncthreads();
        epilogue(b1);
        __syncthreads();
    }

    // ---- layers 2 & 3: K=256 ----
    #pragma unroll 1
    for (int layer = 0; layer < 2; ++layer) {
        const unsigned short* __restrict__ W = wt + 8192 + (layer << 16);
        #pragma unroll
        for (int rt = 0; rt < 4; ++rt)
            #pragma unroll
            for (int ct = 0; ct < 4; ++ct) acc[rt][ct] = f32x4{0.f, 0.f, 0.f, 0.f};

        for (int ks = 0; ks < 8; ++ks) {
            s16x8 wfr[4];
            #pragma unroll
            for (int rt = 0; rt < 4; ++rt)
                wfr[rt] = *reinterpret_cast<const s16x8*>(
                    W + (rowb + rt * 16 + arow) * 256 + ks * 32 + kgrp * 8);
            #pragma unroll
            for (int ct = 0; ct < 4; ++ct) {
                const int p = ct * 16 + bcol;
                const s16x8 bfr = *reinterpret_cast<const s16x8*>(
                    sAb + p * 512 + (((unsigned)(ks * 64 + kgrp * 16)) ^ ((unsigned)((p & 7) << 4))));
                #pragma unroll
                for (int rt = 0; rt < 4; ++rt)
                    acc[rt][ct] = mfma_bf16(wfr[rt], bfr, acc[rt][ct]);
            }
        }
        __syncthreads();
        epilogue(layer == 0 ? b2 : b3);
        __syncthreads();
    }

    // ---- layer 4 via MFMA: A = w4t[16][256] (rows 3-15 zero), B = this wave's 16 points ----
    {
        const unsigned short* __restrict__ W4 = wt + 139264;
        const int p = wid * 16 + bcol;        // this wave's point
        f32x4 a4 = f32x4{0.f, 0.f, 0.f, 0.f};
        #pragma unroll
        for (int ks = 0; ks < 8; ++ks) {
            const s16x8 wfr = *reinterpret_cast<const s16x8*>(W4 + arow * 256 + ks * 32 + kgrp * 8);
            const s16x8 bfr = *reinterpret_cast<const s16x8*>(
                sAb + p * 512 + (((unsigned)(ks * 64 + kgrp * 16)) ^ ((unsigned)((p & 7) << 4))));
            a4 = mfma_bf16(wfr, bfr, a4);
        }
        // D row = kgrp*4 + r, col = bcol -> channels 0-2 live in kgrp==0 lanes, regs 0-2
        if (kgrp == 0) {
            const int pi = p0 + p;
            if (pi < N) {
                #pragma unroll
                for (int c = 0; c < 3; ++c) {
                    const float z = a4[c] + b4[c];
                    out[pi * 3 + c] = 1.0f / (1.0f + expf(-z));
                }
            }
        }
    }
}

// ---- fused fallback (fp32 table, weights in ws) — only if ws can't hold table+feat ----
__global__ __launch_bounds__(NTHREADS, 3)
void fused_hashmlp(const float* __restrict__ x, const float* __restrict__ table,
                   const unsigned short* __restrict__ wt,
                   const float* __restrict__ b1, const float* __restrict__ b2,
                   const float* __restrict__ b3,
                   const float* __restrict__ w4, const float* __restrict__ b4,
                   float* __restrict__ out, int N)
{
    __shared__ float sX[BR][3];
    __shared__ unsigned short sA[BR * 256];
    const int tid = threadIdx.x;
    const int p0  = blockIdx.x * BR;
    if (p0 >= N) return;
    char* sAb = (char*)sA;

    if (tid < BR * 3) sX[tid / 3][tid % 3] = x[p0 * 3 + tid];
    __syncthreads();

    #pragma unroll
    for (int it = 0; it < 4; ++it) {
        const int task = it * NTHREADS + tid;
        const int l = task >> 6;
        const int p = task & 63;
        const float sc  = c_scale[l];
        const float inv = (1.0f / 1.5f);
        const float px = sX[p][0] * inv * sc + 0.5f;
        const float py = sX[p][1] * inv * sc + 0.5f;
        const float pz = sX[p][2] * inv * sc + 0.5f;
        const float fx = floorf(px), fy = floorf(py), fz = floorf(pz);
        const float rx = px - fx, ry = py - fy, rz = pz - fz;
        const unsigned ux = (unsigned)fx, uy = (unsigned)fy, uz = (unsigned)fz;
        const unsigned off = c_off[l];
        const unsigned r1  = c_res1[l];
        const bool dense = (l < 5);
        float ax = 0.0f, ay = 0.0f;
        #pragma unroll
        for (int c = 0; c < 8; ++c) {
            const unsigned bx = c & 1, by = (c >> 1) & 1, bz = (c >> 2) & 1;
            const unsigned cx = ux + bx, cy = uy + by, cz = uz + bz;
            const float wx = bx ? rx : (1.0f - rx);
            const float wy = by ? ry : (1.0f - ry);
            const float wz = bz ? rz : (1.0f - rz);
            const float w = wx * wy * wz;
            unsigned idx;
            if (dense) idx = cx + cy * r1 + cz * r1 * r1;
            else       idx = (cx ^ (cy * 2654435761u) ^ (cz * 805459861u)) & 524287u;
            const float2 tv = *reinterpret_cast<const float2*>(table + 2u * (idx + off));
            ax = fmaf(w, tv.x, ax);
            ay = fmaf(w, tv.y, ay);
        }
        const unsigned pack = (unsigned)f2bf(ax) | ((unsigned)f2bf(ay) << 16);
        *reinterpret_cast<unsigned*>(sAb + p * 512 + ((l * 4) ^ ((p & 7) << 4))) = pack;
    }
    __syncthreads();

    const int lane = tid & 63;
    const int wid  = tid >> 6;
    const int rowb = wid * 64;
    const int arow = lane & 15;
    const int kgrp = lane >> 4;
    const int bcol = lane & 15;

    f32x4 acc[4][4];

    auto epilogue = [&](const float* __restrict__ bias) {
        #pragma unroll
        for (int rt = 0; rt < 4; ++rt) {
            const int f0 = rowb + rt * 16 + kgrp * 4;
            const float4 bv = *reinterpret_cast<const float4*>(bias + f0);
            #pragma unroll
            for (int ct = 0; ct < 4; ++ct) {
                const int p = ct * 16 + bcol;
                const float v0 = fmaxf(acc[rt][ct][0] + bv.x, 0.0f);
                const float v1 = fmaxf(acc[rt][ct][1] + bv.y, 0.0f);
                const float v2 = fmaxf(acc[rt][ct][2] + bv.z, 0.0f);
                const float v3 = fmaxf(acc[rt][ct][3] + bv.w, 0.0f);
                uint2 pk;
                pk.x = (unsigned)f2bf(v0) | ((unsigned)f2bf(v1) << 16);
                pk.y = (unsigned)f2bf(v2) | ((unsigned)f2bf(v3) << 16);
                *reinterpret_cast<uint2*>(
                    sAb + p * 512 + (((unsigned)(2 * f0)) ^ ((unsigned)((p & 7) << 4)))) = pk;
            }
        }
    };

    {
        #pragma unroll
        for (int rt = 0; rt < 4; ++rt)
            #pragma unroll
            for (int ct = 0; ct < 4; ++ct) acc[rt][ct] = f32x4{0.f, 0.f, 0.f, 0.f};
        s16x8 wfr[4];
        #pragma unroll
        for (int rt = 0; rt < 4; ++rt)
            wfr[rt] = *reinterpret_cast<const s16x8*>(wt + (rowb + rt * 16 + arow) * 32 + kgrp * 8);
        #pragma unroll
        for (int ct = 0; ct < 4; ++ct) {
            const int p = ct * 16 + bcol;
            const s16x8 bfr = *reinterpret_cast<const s16x8*>(
                sAb + p * 512 + (((unsigned)(kgrp * 16)) ^ ((unsigned)((p & 7) << 4))));
            #pragma unroll
            for (int rt = 0; rt < 4; ++rt)
                acc[rt][ct] = mfma_bf16(wfr[rt], bfr, acc[rt][ct]);
        }
        __syncthreads();
        epilogue(b1);
        __syncthreads();
    }

    #pragma unroll 1
    for (int layer = 0; layer < 2; ++layer) {
        const unsigned short* __restrict__ W = wt + 8192 + (layer << 16);
        #pragma unroll
        for (int rt = 0; rt < 4; ++rt)
            #pragma unroll
            for (int ct = 0; ct < 4; ++ct) acc[rt][ct] = f32x4{0.f, 0.f, 0.f, 0.f};
        for (int ks = 0; ks < 8; ++ks) {
            s16x8 wfr[4];
            #pragma unroll
            for (int rt = 0; rt < 4; ++rt)
                wfr[rt] = *reinterpret_cast<const s16x8*>(
                    W + (rowb + rt * 16 + arow) * 256 + ks * 32 + kgrp * 8);
            #pragma unroll
            for (int ct = 0; ct < 4; ++ct) {
                const int p = ct * 16 + bcol;
                const s16x8 bfr = *reinterpret_cast<const s16x8*>(
                    sAb + p * 512 + (((unsigned)(ks * 64 + kgrp * 16)) ^ ((unsigned)((p & 7) << 4))));
                #pragma unroll
                for (int rt = 0; rt < 4; ++rt)
                    acc[rt][ct] = mfma_bf16(wfr[rt], bfr, acc[rt][ct]);
            }
        }
        __syncthreads();
        epilogue(layer == 0 ? b2 : b3);
        __syncthreads();
    }

    if (tid < BR * 3) {
        const int r = tid / 3;
        const int c = tid - 3 * r;
        float z0 = 0.0f, z1 = 0.0f;
        for (int kb = 0; kb < 32; kb += 2) {
            const s16x8 hv0 = *reinterpret_cast<const s16x8*>(
                sAb + r * 512 + (((unsigned)(kb * 16)) ^ ((unsigned)((r & 7) << 4))));
            const s16x8 hv1 = *reinterpret_cast<const s16x8*>(
                sAb + r * 512 + (((unsigned)((kb + 1) * 16)) ^ ((unsigned)((r & 7) << 4))));
            #pragma unroll
            for (int j = 0; j < 8; ++j) {
                z0 = fmaf(bf2f((unsigned short)hv0[j]), w4[(kb * 8 + j) * 3 + c], z0);
                z1 = fmaf(bf2f((unsigned short)hv1[j]), w4[((kb + 1) * 8 + j) * 3 + c], z1);
            }
        }
        const float z = z0 + z1 + b4[c];
        const int pi = p0 + r;
        if (pi < N) out[pi * 3 + c] = 1.0f / (1.0f + expf(-z));
    }
}

extern "C" void kernel_launch(void* const* d_in, const int* in_sizes, int n_in,
                              void* d_out, int out_size, void* d_ws, size_t ws_size,
                              hipStream_t stream) {
    const float* x     = (const float*)d_in[0];
    const float* table = (const float*)d_in[1];
    const float* w1    = (const float*)d_in[2];
    const float* b1    = (const float*)d_in[3];
    const float* w2    = (const float*)d_in[4];
    const float* b2    = (const float*)d_in[5];
    const float* w3    = (const float*)d_in[6];
    const float* b3    = (const float*)d_in[7];
    const float* w4    = (const float*)d_in[8];
    const float* b4    = (const float*)d_in[9];
    float* out = (float*)d_out;

    const int N = in_sizes[0] / 3;

    const size_t W_ELEMS    = 143360;                     // bf16 weight elems (incl w4t)
    const size_t TOTAL_E    = 6119864;                    // table entries
    const size_t wt_bytes   = W_ELEMS * 2;                // 286720
    const size_t tbl_bytes  = TOTAL_E * 2;                // fp8 pairs: 2B/entry
    const size_t need_bf    = wt_bytes + tbl_bytes;       // 12526448 (8B-aligned)
    const size_t FEAT_BYTES = (size_t)N * 64;             // uint2[8][N]
    const size_t need_split = need_bf + FEAT_BYTES;       // ~46 MB

    unsigned short* wsw  = (unsigned short*)d_ws;
    unsigned short* tbf8 = (unsigned short*)((char*)d_ws + wt_bytes);
    uint2* feat2 = (uint2*)((char*)d_ws + need_bf);

    hipLaunchKernelGGL(convert_w, dim3(560), dim3(256), 0, stream, w1, w2, w3, w4, wsw);

    if (ws_size >= need_split) {
        hipLaunchKernelGGL(convert_table_fp8, dim3((unsigned)((TOTAL_E + 255) / 256)), dim3(256),
                           0, stream, table, tbf8, (int)TOTAL_E);
        hipLaunchKernelGGL(encode_kernel, dim3((N + 255) / 256, 8), dim3(256), 0, stream,
                           x, tbf8, feat2, N);
        hipLaunchKernelGGL(mlp_kernel, dim3((N + BR - 1) / BR), dim3(NTHREADS), 0, stream,
                           feat2, wsw, b1, b2, b3, b4, out, N);
    } else {
        hipLaunchKernelGGL(fused_hashmlp, dim3((N + BR - 1) / BR), dim3(NTHREADS), 0, stream,
                           x, table, wsw, b1, b2, b3, w4, b4, out, N);
    }
}